// Round 1
// baseline (1633.909 us; speedup 1.0000x reference)
//
#include <hip/hip_runtime.h>

// DCRNN cell: 3x diffusion conv (fwd/bwd, K=3 Chebyshev) + GRU gating.
// N=50000 nodes, E=800000 edges, F_IN=32, F_OUT=64, fan=96.

#define NTHREADS 256

// ---------------------------------------------------------------- utilities

// Detect whether edge_index was staged as int64 (high dwords all zero) or int32.
__global__ void detect_i64_kernel(const int* ei, int n_check, int* flag) {
    __shared__ int any;
    if (threadIdx.x == 0) any = 0;
    __syncthreads();
    int local = 0;
    for (int i = threadIdx.x; i < n_check; i += blockDim.x)
        if (ei[2 * i + 1] != 0) local = 1;
    if (local) any = 1;
    __syncthreads();
    if (threadIdx.x == 0) *flag = (any ? 0 : 1);  // 1 => int64 layout
}

__global__ void repack_kernel(const int* ei, const int* __restrict__ flag,
                              int* row32, int* col32, int E) {
    int e = blockIdx.x * blockDim.x + threadIdx.x;
    if (e >= E) return;
    if (*flag) {
        const long long* p = (const long long*)ei;
        row32[e] = (int)p[e];
        col32[e] = (int)p[E + e];
    } else {
        row32[e] = ei[e];
        col32[e] = ei[E + e];
    }
}

// Degrees (weighted) + CSR histogram counts.
__global__ void deg_hist_kernel(const int* __restrict__ row, const int* __restrict__ col,
                                const float* __restrict__ ew,
                                float* deg_out, float* deg_in, int* cnt_f, int* cnt_b, int E) {
    int e = blockIdx.x * blockDim.x + threadIdx.x;
    if (e >= E) return;
    int r = row[e], c = col[e];
    float w = ew[e];
    atomicAdd(&deg_out[r], w);
    atomicAdd(&deg_in[c], w);
    atomicAdd(&cnt_f[c], 1);   // forward CSR grouped by dst=col
    atomicAdd(&cnt_b[r], 1);   // backward CSR grouped by dst=row
}

// Exclusive scan of two count arrays (single block, 1024 threads, Hillis-Steele chunks).
__global__ void scan_kernel(const int* __restrict__ cf, const int* __restrict__ cb,
                            int* of, int* ob, int* curf, int* curb, int N) {
    __shared__ int sf[1024], sb[1024];
    int t = threadIdx.x;
    int carryf = 0, carryb = 0;
    for (int base = 0; base < N; base += 1024) {
        int i = base + t;
        int vf = (i < N) ? cf[i] : 0;
        int vb = (i < N) ? cb[i] : 0;
        sf[t] = vf; sb[t] = vb;
        __syncthreads();
        for (int d = 1; d < 1024; d <<= 1) {
            int xf = (t >= d) ? sf[t - d] : 0;
            int xb = (t >= d) ? sb[t - d] : 0;
            __syncthreads();
            sf[t] += xf; sb[t] += xb;
            __syncthreads();
        }
        if (i < N) {
            int ef = carryf + sf[t] - vf;
            int eb = carryb + sb[t] - vb;
            of[i] = ef; ob[i] = eb;
            curf[i] = ef; curb[i] = eb;
        }
        carryf += sf[1023];
        carryb += sb[1023];
        __syncthreads();
    }
    if (t == 0) { of[N] = carryf; ob[N] = carryb; }
}

// Fill CSR payloads; edge coefficients computed on the fly.
__global__ void scatter_kernel(const int* __restrict__ row, const int* __restrict__ col,
                               const float* __restrict__ ew,
                               const float* __restrict__ deg_out, const float* __restrict__ deg_in,
                               int* curf, int* curb,
                               int* srcf, float* wf, int* srcb, float* wb, int E) {
    int e = blockIdx.x * blockDim.x + threadIdx.x;
    if (e >= E) return;
    int r = row[e], c = col[e];
    float w = ew[e];
    float fcf = w / deg_out[r];  // forward coeff
    float fcb = w / deg_in[c];   // backward coeff
    int pf = atomicAdd(&curf[c], 1);
    srcf[pf] = r; wf[pf] = fcf;
    int pb = atomicAdd(&curb[r], 1);
    srcb[pb] = c; wb[pb] = fcb;
}

// XH = [X | H] (or [X | H*R] when R != nullptr), row = 96 floats = 24 float4.
__global__ void build_xh_kernel(const float4* __restrict__ X4, const float4* __restrict__ H4,
                                const float4* __restrict__ R4, float4* __restrict__ XH4, int N) {
    int idx = blockIdx.x * blockDim.x + threadIdx.x;
    if (idx >= N * 24) return;
    int n = idx / 24, c = idx % 24;
    float4 v;
    if (c < 8) {
        v = X4[n * 8 + c];
    } else {
        v = H4[n * 16 + (c - 8)];
        if (R4) {
            float4 r = R4[n * 16 + (c - 8)];
            v.x *= r.x; v.y *= r.y; v.z *= r.z; v.w *= r.w;
        }
    }
    XH4[idx] = v;
}

// out[n] = sum_{e in CSR[n]} w[e] * x[src[e]]   (optionally 2*sum - base[n]).
// blockDim = (24, 8): 24 float4 lanes cover the 96-dim row.
template <int CHEBY>
__global__ void gather_prop_kernel(const float4* __restrict__ x4, const int* __restrict__ offs,
                                   const int* __restrict__ src, const float* __restrict__ wgt,
                                   const float4* __restrict__ base4, float4* __restrict__ out4,
                                   int N) {
    int n = blockIdx.x * blockDim.y + threadIdx.y;
    if (n >= N) return;
    int c = threadIdx.x;
    int s0 = offs[n], s1 = offs[n + 1];
    float4 acc = make_float4(0.f, 0.f, 0.f, 0.f);
    for (int o = s0; o < s1; ++o) {
        float w = wgt[o];
        int s = src[o];
        float4 v = x4[s * 24 + c];
        acc.x += w * v.x; acc.y += w * v.y; acc.z += w * v.z; acc.w += w * v.w;
    }
    int oi = n * 24 + c;
    if (CHEBY) {
        float4 b = base4[oi];
        acc.x = 2.f * acc.x - b.x; acc.y = 2.f * acc.y - b.y;
        acc.z = 2.f * acc.z - b.z; acc.w = 2.f * acc.w - b.w;
    }
    out4[oi] = acc;
}

// C (+)= A[N,96] @ (W1+W2)[96,64] (+ bias). W staged in LDS; 4 rows/thread reg-blocked.
template <bool INIT>
__global__ __launch_bounds__(256) void gemm_acc_kernel(const float* __restrict__ A,
                                                       const float* __restrict__ W1,
                                                       const float* __restrict__ W2,
                                                       const float* __restrict__ bias,
                                                       float* __restrict__ C, int N) {
    __shared__ float wl[96 * 64];
    int t = threadIdx.y * 64 + threadIdx.x;
    for (int i = t; i < 96 * 64; i += 256)
        wl[i] = W2 ? (W1[i] + W2[i]) : W1[i];
    __syncthreads();
    int o = threadIdx.x;
    int rowBase = blockIdx.x * 64;
    float b = 0.f;
    if (INIT && bias) b = bias[o];
    for (int g = 0; g < 4; ++g) {
        int r0 = rowBase + g * 16 + threadIdx.y * 4;
        if (r0 >= N) continue;  // N % 4 == 0, so groups are all-or-nothing
        const float* a = A + (size_t)r0 * 96;
        float acc0 = 0, acc1 = 0, acc2 = 0, acc3 = 0;
#pragma unroll
        for (int f = 0; f < 96; f += 4) {
            float4 v0 = *(const float4*)(a + f);
            float4 v1 = *(const float4*)(a + 96 + f);
            float4 v2 = *(const float4*)(a + 192 + f);
            float4 v3 = *(const float4*)(a + 288 + f);
            float w0 = wl[f * 64 + o], w1 = wl[(f + 1) * 64 + o];
            float w2 = wl[(f + 2) * 64 + o], w3 = wl[(f + 3) * 64 + o];
            acc0 += v0.x * w0 + v0.y * w1 + v0.z * w2 + v0.w * w3;
            acc1 += v1.x * w0 + v1.y * w1 + v1.z * w2 + v1.w * w3;
            acc2 += v2.x * w0 + v2.y * w1 + v2.z * w2 + v2.w * w3;
            acc3 += v3.x * w0 + v3.y * w1 + v3.z * w2 + v3.w * w3;
        }
        float* cp = C + (size_t)r0 * 64 + o;
        if (INIT) {
            cp[0] = acc0 + b; cp[64] = acc1 + b; cp[128] = acc2 + b; cp[192] = acc3 + b;
        } else {
            cp[0] += acc0; cp[64] += acc1; cp[128] += acc2; cp[192] += acc3;
        }
    }
}

__global__ void sigmoid_kernel(float* p, int n) {
    int i = blockIdx.x * blockDim.x + threadIdx.x;
    if (i < n) p[i] = 1.f / (1.f + __expf(-p[i]));
}

__global__ void final_kernel(const float* __restrict__ Z, const float* __restrict__ H,
                             const float* __restrict__ Acc, float* __restrict__ out, int n) {
    int i = blockIdx.x * blockDim.x + threadIdx.x;
    if (i < n) {
        float z = Z[i];
        out[i] = z * H[i] + (1.f - z) * tanhf(Acc[i]);
    }
}

// ---------------------------------------------------------------- launch

extern "C" void kernel_launch(void* const* d_in, const int* in_sizes, int n_in,
                              void* d_out, int out_size, void* d_ws, size_t ws_size,
                              hipStream_t stream) {
    const float* X  = (const float*)d_in[0];
    const int*   ei = (const int*)d_in[1];
    const float* ew = (const float*)d_in[2];
    const float* H  = (const float*)d_in[3];
    const float* Wz = (const float*)d_in[4];
    const float* bz = (const float*)d_in[5];
    const float* Wr = (const float*)d_in[6];
    const float* br = (const float*)d_in[7];
    const float* Wh = (const float*)d_in[8];
    const float* bh = (const float*)d_in[9];
    float* out = (float*)d_out;

    const int N = in_sizes[0] / 32;   // 50000
    const int E = in_sizes[2];        // 800000
    const int KS = 96 * 64;           // per-(direction,hop) weight stride

    // ---- workspace carve (256B aligned) ----
    char* wp = (char*)d_ws;
    auto alloc = [&](size_t nbytes) -> void* {
        void* p = (void*)wp;
        wp += (nbytes + 255) & ~(size_t)255;
        return p;
    };
    float* XH   = (float*)alloc((size_t)N * 96 * 4);
    float* T1o  = (float*)alloc((size_t)N * 96 * 4);
    float* T1i  = (float*)alloc((size_t)N * 96 * 4);
    float* S    = (float*)alloc((size_t)N * 96 * 4);
    float* AccZ = (float*)alloc((size_t)N * 64 * 4);
    float* AccR = (float*)alloc((size_t)N * 64 * 4);  // later reused as AccH
    float* deg_out = (float*)alloc((size_t)N * 4);
    float* deg_in  = (float*)alloc((size_t)N * 4);
    int* cnt_f  = (int*)alloc((size_t)N * 4);
    int* cnt_b  = (int*)alloc((size_t)N * 4);
    int* offs_f = (int*)alloc((size_t)(N + 1) * 4);
    int* offs_b = (int*)alloc((size_t)(N + 1) * 4);
    int* cur_f  = (int*)alloc((size_t)N * 4);
    int* cur_b  = (int*)alloc((size_t)N * 4);
    int* src_f  = (int*)alloc((size_t)E * 4);
    float* wgt_f = (float*)alloc((size_t)E * 4);
    int* src_b  = (int*)alloc((size_t)E * 4);
    float* wgt_b = (float*)alloc((size_t)E * 4);
    int* row32  = (int*)alloc((size_t)E * 4);
    int* col32  = (int*)alloc((size_t)E * 4);
    int* flag   = (int*)alloc(256);

    const int eBlocks = (E + NTHREADS - 1) / NTHREADS;
    const int xhBlocks = (N * 24 + NTHREADS - 1) / NTHREADS;
    const int gemmBlocks = (N + 63) / 64;
    const int nfBlocks = (N * 64 + NTHREADS - 1) / NTHREADS;
    dim3 gatherBlock(24, 8);
    const int gatherBlocks = (N + 7) / 8;

    // ---- edge preprocessing (shared by all three dconvs) ----
    hipMemsetAsync(deg_out, 0, (size_t)N * 4, stream);
    hipMemsetAsync(deg_in, 0, (size_t)N * 4, stream);
    hipMemsetAsync(cnt_f, 0, (size_t)N * 4, stream);
    hipMemsetAsync(cnt_b, 0, (size_t)N * 4, stream);

    detect_i64_kernel<<<1, 256, 0, stream>>>(ei, E < 8192 ? E : 8192, flag);
    repack_kernel<<<eBlocks, NTHREADS, 0, stream>>>(ei, flag, row32, col32, E);
    deg_hist_kernel<<<eBlocks, NTHREADS, 0, stream>>>(row32, col32, ew, deg_out, deg_in, cnt_f, cnt_b, E);
    scan_kernel<<<1, 1024, 0, stream>>>(cnt_f, cnt_b, offs_f, offs_b, cur_f, cur_b, N);
    scatter_kernel<<<eBlocks, NTHREADS, 0, stream>>>(row32, col32, ew, deg_out, deg_in,
                                                     cur_f, cur_b, src_f, wgt_f, src_b, wgt_b, E);

    const float4* X4 = (const float4*)X;
    const float4* H4 = (const float4*)H;

    // ---- phase ZR: shared T matrices on XH = [X|H] ----
    build_xh_kernel<<<xhBlocks, NTHREADS, 0, stream>>>(X4, H4, nullptr, (float4*)XH, N);

    gather_prop_kernel<0><<<gatherBlocks, gatherBlock, 0, stream>>>(
        (const float4*)XH, offs_f, src_f, wgt_f, nullptr, (float4*)T1o, N);
    gather_prop_kernel<0><<<gatherBlocks, gatherBlock, 0, stream>>>(
        (const float4*)XH, offs_b, src_b, wgt_b, nullptr, (float4*)T1i, N);

    // hop-0: W[0,0]+W[1,0] fused in LDS load
    gemm_acc_kernel<true><<<gemmBlocks, dim3(64, 4), 0, stream>>>(XH, Wz, Wz + 3 * KS, bz, AccZ, N);
    gemm_acc_kernel<true><<<gemmBlocks, dim3(64, 4), 0, stream>>>(XH, Wr, Wr + 3 * KS, br, AccR, N);
    // hop-1
    gemm_acc_kernel<false><<<gemmBlocks, dim3(64, 4), 0, stream>>>(T1o, Wz + 1 * KS, nullptr, nullptr, AccZ, N);
    gemm_acc_kernel<false><<<gemmBlocks, dim3(64, 4), 0, stream>>>(T1o, Wr + 1 * KS, nullptr, nullptr, AccR, N);
    gemm_acc_kernel<false><<<gemmBlocks, dim3(64, 4), 0, stream>>>(T1i, Wz + 4 * KS, nullptr, nullptr, AccZ, N);
    gemm_acc_kernel<false><<<gemmBlocks, dim3(64, 4), 0, stream>>>(T1i, Wr + 4 * KS, nullptr, nullptr, AccR, N);
    // hop-2 forward: S = 2*prop_f(T1o) - XH
    gather_prop_kernel<1><<<gatherBlocks, gatherBlock, 0, stream>>>(
        (const float4*)T1o, offs_f, src_f, wgt_f, (const float4*)XH, (float4*)S, N);
    gemm_acc_kernel<false><<<gemmBlocks, dim3(64, 4), 0, stream>>>(S, Wz + 2 * KS, nullptr, nullptr, AccZ, N);
    gemm_acc_kernel<false><<<gemmBlocks, dim3(64, 4), 0, stream>>>(S, Wr + 2 * KS, nullptr, nullptr, AccR, N);
    // hop-2 backward: S = 2*prop_b(T1i) - XH
    gather_prop_kernel<1><<<gatherBlocks, gatherBlock, 0, stream>>>(
        (const float4*)T1i, offs_b, src_b, wgt_b, (const float4*)XH, (float4*)S, N);
    gemm_acc_kernel<false><<<gemmBlocks, dim3(64, 4), 0, stream>>>(S, Wz + 5 * KS, nullptr, nullptr, AccZ, N);
    gemm_acc_kernel<false><<<gemmBlocks, dim3(64, 4), 0, stream>>>(S, Wr + 5 * KS, nullptr, nullptr, AccR, N);

    sigmoid_kernel<<<nfBlocks, NTHREADS, 0, stream>>>(AccZ, N * 64);  // -> Z
    sigmoid_kernel<<<nfBlocks, NTHREADS, 0, stream>>>(AccR, N * 64);  // -> R

    // ---- phase H: XHR = [X | H*R] ----
    build_xh_kernel<<<xhBlocks, NTHREADS, 0, stream>>>(X4, H4, (const float4*)AccR, (float4*)XH, N);

    gather_prop_kernel<0><<<gatherBlocks, gatherBlock, 0, stream>>>(
        (const float4*)XH, offs_f, src_f, wgt_f, nullptr, (float4*)T1o, N);
    gather_prop_kernel<0><<<gatherBlocks, gatherBlock, 0, stream>>>(
        (const float4*)XH, offs_b, src_b, wgt_b, nullptr, (float4*)T1i, N);

    gemm_acc_kernel<true><<<gemmBlocks, dim3(64, 4), 0, stream>>>(XH, Wh, Wh + 3 * KS, bh, AccR, N);
    gemm_acc_kernel<false><<<gemmBlocks, dim3(64, 4), 0, stream>>>(T1o, Wh + 1 * KS, nullptr, nullptr, AccR, N);
    gemm_acc_kernel<false><<<gemmBlocks, dim3(64, 4), 0, stream>>>(T1i, Wh + 4 * KS, nullptr, nullptr, AccR, N);

    gather_prop_kernel<1><<<gatherBlocks, gatherBlock, 0, stream>>>(
        (const float4*)T1o, offs_f, src_f, wgt_f, (const float4*)XH, (float4*)S, N);
    gemm_acc_kernel<false><<<gemmBlocks, dim3(64, 4), 0, stream>>>(S, Wh + 2 * KS, nullptr, nullptr, AccR, N);
    gather_prop_kernel<1><<<gatherBlocks, gatherBlock, 0, stream>>>(
        (const float4*)T1i, offs_b, src_b, wgt_b, (const float4*)XH, (float4*)S, N);
    gemm_acc_kernel<false><<<gemmBlocks, dim3(64, 4), 0, stream>>>(S, Wh + 5 * KS, nullptr, nullptr, AccR, N);

    final_kernel<<<nfBlocks, NTHREADS, 0, stream>>>(AccZ, H, AccR, out, N * 64);
}

// Round 2
// 1471.217 us; speedup vs baseline: 1.1106x; 1.1106x over previous
//
#include <hip/hip_runtime.h>

// DCRNN cell: 3x diffusion conv (fwd/bwd, K=3 Chebyshev) + GRU gating.
// N=50000 nodes, E=800000 edges, F_IN=32, F_OUT=64, fan=96.

#define NTHREADS 256
#define GEMM_ROWS 224   // 7 groups of 32 rows; grid = ceil(N/224) = 224 blocks

__device__ __forceinline__ float sigmoidf_(float x) { return 1.f / (1.f + __expf(-x)); }

// ---------------------------------------------------------------- edge decode

__device__ __forceinline__ void load_edge(const int* ei, int e, int E, int i64,
                                          int& r, int& c) {
    if (i64) {
        const long long* p = (const long long*)ei;
        r = (int)p[e]; c = (int)p[E + e];
    } else {
        r = ei[e]; c = ei[E + e];
    }
}

// Detect whether edge_index was staged as int64 (high dwords all zero) or int32.
__global__ void detect_i64_kernel(const int* ei, int n_check, int* flag) {
    __shared__ int any;
    if (threadIdx.x == 0) any = 0;
    __syncthreads();
    int local = 0;
    for (int i = threadIdx.x; i < n_check; i += blockDim.x)
        if (ei[2 * i + 1] != 0) local = 1;
    if (local) any = 1;  // benign race
    __syncthreads();
    if (threadIdx.x == 0) *flag = (any ? 0 : 1);  // 1 => int64 layout
}

// Degrees (weighted) + CSR histogram counts.
__global__ void deg_hist_kernel(const int* __restrict__ ei, const int* __restrict__ flag,
                                const float* __restrict__ ew,
                                float* deg_out, float* deg_in, int* cnt_f, int* cnt_b, int E) {
    int e = blockIdx.x * blockDim.x + threadIdx.x;
    if (e >= E) return;
    int i64 = *flag;
    int r, c; load_edge(ei, e, E, i64, r, c);
    float w = ew[e];
    atomicAdd(&deg_out[r], w);
    atomicAdd(&deg_in[c], w);
    atomicAdd(&cnt_f[c], 1);   // forward CSR grouped by dst=col
    atomicAdd(&cnt_b[r], 1);   // backward CSR grouped by dst=row
}

// Exclusive scan: thread-serial chunks + one block scan (1 block, 1024 threads).
__global__ void scan_kernel(const int* __restrict__ cf, const int* __restrict__ cb,
                            int* of, int* ob, int* curf, int* curb, int N) {
    __shared__ int sf[1024], sb[1024];
    int t = threadIdx.x;
    int CH = (N + 1023) >> 10;
    int beg = t * CH, end = min(beg + CH, N);
    if (beg > N) beg = N;
    int sumf = 0, sumb = 0;
    for (int i = beg; i < end; ++i) { sumf += cf[i]; sumb += cb[i]; }
    sf[t] = sumf; sb[t] = sumb;
    __syncthreads();
    for (int d = 1; d < 1024; d <<= 1) {
        int xf = (t >= d) ? sf[t - d] : 0;
        int xb = (t >= d) ? sb[t - d] : 0;
        __syncthreads();
        sf[t] += xf; sb[t] += xb;
        __syncthreads();
    }
    int exf = sf[t] - sumf, exb = sb[t] - sumb;  // exclusive offset of this chunk
    for (int i = beg; i < end; ++i) {
        int vf = cf[i], vb = cb[i];
        of[i] = exf; curf[i] = exf; exf += vf;
        ob[i] = exb; curb[i] = exb; exb += vb;
    }
    if (t == 1023) { of[N] = exf; ob[N] = exb; }
}

// Fill CSR payloads as (src, coeff) pairs; coefficients computed on the fly.
__global__ void scatter_kernel(const int* __restrict__ ei, const int* __restrict__ flag,
                               const float* __restrict__ ew,
                               const float* __restrict__ deg_out, const float* __restrict__ deg_in,
                               int* curf, int* curb, int2* pf, int2* pb, int E) {
    int e = blockIdx.x * blockDim.x + threadIdx.x;
    if (e >= E) return;
    int i64 = *flag;
    int r, c; load_edge(ei, e, E, i64, r, c);
    float w = ew[e];
    int ipf = atomicAdd(&curf[c], 1);
    pf[ipf] = make_int2(r, __float_as_int(w / deg_out[r]));
    int ipb = atomicAdd(&curb[r], 1);
    pb[ipb] = make_int2(c, __float_as_int(w / deg_in[c]));
}

// XH = [X | H], row = 96 floats = 24 float4.
__global__ void build_xh_kernel(const float4* __restrict__ X4, const float4* __restrict__ H4,
                                float4* __restrict__ XH4, int N) {
    int idx = blockIdx.x * blockDim.x + threadIdx.x;
    if (idx >= N * 24) return;
    int n = idx / 24, c = idx % 24;
    XH4[idx] = (c < 8) ? X4[n * 8 + c] : H4[n * 16 + (c - 8)];
}

// Dual-direction gather: blockIdx.y selects (fwd, bwd) CSR.
// out[n] = sum_e w[e] * x[src[e]]   (CHEBY: 2*sum - base[n]).
template <int CHEBY>
__global__ __launch_bounds__(384) void gather2_kernel(
    const float4* __restrict__ xf, const float4* __restrict__ xb,
    const int* __restrict__ offs_f, const int2* __restrict__ pf,
    const int* __restrict__ offs_b, const int2* __restrict__ pb,
    const float4* __restrict__ base4, float4* __restrict__ outf, float4* __restrict__ outb,
    int N) {
    const float4* x4; const int* offs; const int2* pr; float4* out4;
    if (blockIdx.y == 0) { x4 = xf; offs = offs_f; pr = pf; out4 = outf; }
    else                 { x4 = xb; offs = offs_b; pr = pb; out4 = outb; }
    int n = blockIdx.x * 16 + threadIdx.y;
    if (n >= N) return;
    int c = threadIdx.x;  // 0..23
    int s0 = offs[n], s1 = offs[n + 1];
    float4 acc = make_float4(0.f, 0.f, 0.f, 0.f);
    int o = s0;
    for (; o + 2 <= s1; o += 2) {
        int2 p0 = pr[o], p1 = pr[o + 1];
        float w0 = __int_as_float(p0.y), w1 = __int_as_float(p1.y);
        float4 v0 = x4[(size_t)p0.x * 24 + c];
        float4 v1 = x4[(size_t)p1.x * 24 + c];
        acc.x += w0 * v0.x + w1 * v1.x;
        acc.y += w0 * v0.y + w1 * v1.y;
        acc.z += w0 * v0.z + w1 * v1.z;
        acc.w += w0 * v0.w + w1 * v1.w;
    }
    if (o < s1) {
        int2 p0 = pr[o];
        float w0 = __int_as_float(p0.y);
        float4 v0 = x4[(size_t)p0.x * 24 + c];
        acc.x += w0 * v0.x; acc.y += w0 * v0.y;
        acc.z += w0 * v0.z; acc.w += w0 * v0.w;
    }
    size_t oi = (size_t)n * 24 + c;
    if (CHEBY) {
        float4 b = base4[oi];
        acc.x = 2.f * acc.x - b.x; acc.y = 2.f * acc.y - b.y;
        acc.z = 2.f * acc.z - b.z; acc.w = 2.f * acc.w - b.w;
    }
    out4[oi] = acc;
}

// Fused K=480 GEMM over 5 A-matrices with full [480,64] weight in LDS.
// MODE 0: Out = sigmoid(acc)                     (Z gate)
// MODE 1: Out[:,32:96] = H * sigmoid(acc)        (R gate, writes into XH in place)
// MODE 2: Out = Z*H + (1-Z)*tanh(acc)            (H~ + GRU combine)
template <int MODE>
__global__ __launch_bounds__(512) void gemm5_kernel(
    const float* __restrict__ A0, const float* __restrict__ A1, const float* __restrict__ A2,
    const float* __restrict__ A3, const float* __restrict__ A4,
    const float* __restrict__ W, const float* __restrict__ bias,
    const float* __restrict__ H, const float* __restrict__ Z,
    float* __restrict__ Out, int N) {
    __shared__ float wl[480 * 64];  // layout: float4 index (f4*64 + o)
    const int KS = 96 * 64;
    int t = threadIdx.y * 64 + threadIdx.x;
    for (int i = t; i < 480 * 64; i += 512) {
        int f = i >> 6, o = i & 63;
        int seg = f / 96, fr = f - seg * 96;
        // segment -> weight block: {W0+W3, W1, W4, W2, W5}
        int off;
        if (seg == 0) off = 0;
        else if (seg == 1) off = 1 * KS;
        else if (seg == 2) off = 4 * KS;
        else if (seg == 3) off = 2 * KS;
        else off = 5 * KS;
        float v = W[off + fr * 64 + o];
        if (seg == 0) v += W[3 * KS + fr * 64 + o];
        wl[(f >> 2) * 256 + o * 4 + (f & 3)] = v;
    }
    __syncthreads();
    int o = threadIdx.x;
    float b = bias[o];
    const float* As[5] = {A0, A1, A2, A3, A4};
    const float4* wl4 = (const float4*)wl;
    for (int g = 0; g < 7; ++g) {
        int r0 = blockIdx.x * GEMM_ROWS + g * 32 + threadIdx.y * 4;
        if (r0 >= N) continue;  // N % 4 == 0 so r0..r0+3 all valid when r0 < N
        float acc0 = b, acc1 = b, acc2 = b, acc3 = b;
#pragma unroll
        for (int m = 0; m < 5; ++m) {
            const float* a = As[m] + (size_t)r0 * 96;
#pragma unroll 4
            for (int f4 = 0; f4 < 24; ++f4) {
                float4 w = wl4[(m * 24 + f4) * 64 + o];
                float4 v0 = *(const float4*)(a + f4 * 4);
                float4 v1 = *(const float4*)(a + 96 + f4 * 4);
                float4 v2 = *(const float4*)(a + 192 + f4 * 4);
                float4 v3 = *(const float4*)(a + 288 + f4 * 4);
                acc0 += v0.x * w.x + v0.y * w.y + v0.z * w.z + v0.w * w.w;
                acc1 += v1.x * w.x + v1.y * w.y + v1.z * w.z + v1.w * w.w;
                acc2 += v2.x * w.x + v2.y * w.y + v2.z * w.z + v2.w * w.w;
                acc3 += v3.x * w.x + v3.y * w.y + v3.z * w.z + v3.w * w.w;
            }
        }
        size_t base = (size_t)r0 * 64 + o;
        if (MODE == 0) {
            Out[base]       = sigmoidf_(acc0);
            Out[base + 64]  = sigmoidf_(acc1);
            Out[base + 128] = sigmoidf_(acc2);
            Out[base + 192] = sigmoidf_(acc3);
        } else if (MODE == 1) {
            Out[(size_t)(r0 + 0) * 96 + 32 + o] = H[base]       * sigmoidf_(acc0);
            Out[(size_t)(r0 + 1) * 96 + 32 + o] = H[base + 64]  * sigmoidf_(acc1);
            Out[(size_t)(r0 + 2) * 96 + 32 + o] = H[base + 128] * sigmoidf_(acc2);
            Out[(size_t)(r0 + 3) * 96 + 32 + o] = H[base + 192] * sigmoidf_(acc3);
        } else {
            float z0 = Z[base], z1 = Z[base + 64], z2 = Z[base + 128], z3 = Z[base + 192];
            Out[base]       = z0 * H[base]       + (1.f - z0) * tanhf(acc0);
            Out[base + 64]  = z1 * H[base + 64]  + (1.f - z1) * tanhf(acc1);
            Out[base + 128] = z2 * H[base + 128] + (1.f - z2) * tanhf(acc2);
            Out[base + 192] = z3 * H[base + 192] + (1.f - z3) * tanhf(acc3);
        }
    }
}

// ---------------------------------------------------------------- launch

extern "C" void kernel_launch(void* const* d_in, const int* in_sizes, int n_in,
                              void* d_out, int out_size, void* d_ws, size_t ws_size,
                              hipStream_t stream) {
    const float* X  = (const float*)d_in[0];
    const int*   ei = (const int*)d_in[1];
    const float* ew = (const float*)d_in[2];
    const float* H  = (const float*)d_in[3];
    const float* Wz = (const float*)d_in[4];
    const float* bz = (const float*)d_in[5];
    const float* Wr = (const float*)d_in[6];
    const float* br = (const float*)d_in[7];
    const float* Wh = (const float*)d_in[8];
    const float* bh = (const float*)d_in[9];
    float* out = (float*)d_out;

    const int N = in_sizes[0] / 32;   // 50000
    const int E = in_sizes[2];        // 800000

    // ---- workspace carve (256B aligned) ----
    char* wp = (char*)d_ws;
    auto alloc = [&](size_t nbytes) -> void* {
        void* p = (void*)wp;
        wp += (nbytes + 255) & ~(size_t)255;
        return p;
    };
    float* XH   = (float*)alloc((size_t)N * 96 * 4);  // becomes XHR after R-GEMM
    float* T1o  = (float*)alloc((size_t)N * 96 * 4);
    float* T1i  = (float*)alloc((size_t)N * 96 * 4);
    float* S2o  = (float*)alloc((size_t)N * 96 * 4);
    float* S2i  = (float*)alloc((size_t)N * 96 * 4);
    float* AccZ = (float*)alloc((size_t)N * 64 * 4);
    float* deg_out = (float*)alloc((size_t)N * 4);
    float* deg_in  = (float*)alloc((size_t)N * 4);
    int* cnt_f  = (int*)alloc((size_t)N * 4);
    int* cnt_b  = (int*)alloc((size_t)N * 4);
    int* offs_f = (int*)alloc((size_t)(N + 1) * 4);
    int* offs_b = (int*)alloc((size_t)(N + 1) * 4);
    int* cur_f  = (int*)alloc((size_t)N * 4);
    int* cur_b  = (int*)alloc((size_t)N * 4);
    int2* pair_f = (int2*)alloc((size_t)E * 8);
    int2* pair_b = (int2*)alloc((size_t)E * 8);
    int* flag   = (int*)alloc(256);

    const int eBlocks = (E + NTHREADS - 1) / NTHREADS;
    const int xhBlocks = (N * 24 + NTHREADS - 1) / NTHREADS;
    const int gemmBlocks = (N + GEMM_ROWS - 1) / GEMM_ROWS;
    dim3 gatherBlock(24, 16);
    dim3 gatherGrid((N + 15) / 16, 2);
    dim3 gemmBlockDim(64, 8);

    // ---- edge preprocessing (shared by all three dconvs) ----
    hipMemsetAsync(deg_out, 0, (size_t)N * 4, stream);
    hipMemsetAsync(deg_in, 0, (size_t)N * 4, stream);
    hipMemsetAsync(cnt_f, 0, (size_t)N * 4, stream);
    hipMemsetAsync(cnt_b, 0, (size_t)N * 4, stream);

    detect_i64_kernel<<<1, 256, 0, stream>>>(ei, E < 8192 ? E : 8192, flag);
    deg_hist_kernel<<<eBlocks, NTHREADS, 0, stream>>>(ei, flag, ew, deg_out, deg_in, cnt_f, cnt_b, E);
    scan_kernel<<<1, 1024, 0, stream>>>(cnt_f, cnt_b, offs_f, offs_b, cur_f, cur_b, N);
    scatter_kernel<<<eBlocks, NTHREADS, 0, stream>>>(ei, flag, ew, deg_out, deg_in,
                                                     cur_f, cur_b, pair_f, pair_b, E);

    // ---- phase ZR: shared T matrices on XH = [X|H] ----
    build_xh_kernel<<<xhBlocks, NTHREADS, 0, stream>>>((const float4*)X, (const float4*)H,
                                                       (float4*)XH, N);
    gather2_kernel<0><<<gatherGrid, gatherBlock, 0, stream>>>(
        (const float4*)XH, (const float4*)XH, offs_f, pair_f, offs_b, pair_b,
        nullptr, (float4*)T1o, (float4*)T1i, N);
    gather2_kernel<1><<<gatherGrid, gatherBlock, 0, stream>>>(
        (const float4*)T1o, (const float4*)T1i, offs_f, pair_f, offs_b, pair_b,
        (const float4*)XH, (float4*)S2o, (float4*)S2i, N);

    // Z gate (sigmoid fused)
    gemm5_kernel<0><<<gemmBlocks, gemmBlockDim, 0, stream>>>(
        XH, T1o, T1i, S2o, S2i, Wz, bz, nullptr, nullptr, AccZ, N);
    // R gate: writes H*R into XH's H-columns in place -> XH becomes XHR
    gemm5_kernel<1><<<gemmBlocks, gemmBlockDim, 0, stream>>>(
        XH, T1o, T1i, S2o, S2i, Wr, br, H, nullptr, XH, N);

    // ---- phase H: propagate XHR ----
    gather2_kernel<0><<<gatherGrid, gatherBlock, 0, stream>>>(
        (const float4*)XH, (const float4*)XH, offs_f, pair_f, offs_b, pair_b,
        nullptr, (float4*)T1o, (float4*)T1i, N);
    gather2_kernel<1><<<gatherGrid, gatherBlock, 0, stream>>>(
        (const float4*)T1o, (const float4*)T1i, offs_f, pair_f, offs_b, pair_b,
        (const float4*)XH, (float4*)S2o, (float4*)S2i, N);

    // H~ gate + GRU combine fused
    gemm5_kernel<2><<<gemmBlocks, gemmBlockDim, 0, stream>>>(
        XH, T1o, T1i, S2o, S2i, Wh, bh, H, AccZ, out, N);
}

// Round 3
// 718.910 us; speedup vs baseline: 2.2728x; 2.0465x over previous
//
#include <hip/hip_runtime.h>

// DCRNN cell: 3x diffusion conv (fwd/bwd, K=3 Chebyshev) + GRU gating.
// N=50000 nodes, E=800000 edges, F_IN=32, F_OUT=64, fan=96.
// Round 3: bf16 T-matrices + MFMA GEMM + packed 64b degree atomics.

#define NTHREADS 256

typedef unsigned short u16;
typedef unsigned int u32;
typedef unsigned long long u64;
typedef __attribute__((ext_vector_type(8))) short short8;   // 8 bf16 (4 VGPRs)
typedef __attribute__((ext_vector_type(4))) float f32x4;

#define DEG_SCALE 268435456.0f          // 2^28
#define DEG_INV   3.725290298461914e-9f // 2^-28
#define MASK40    ((1ull << 40) - 1)

__device__ __forceinline__ float sigmoidf_(float x) { return 1.f / (1.f + __expf(-x)); }
__device__ __forceinline__ float b2f_lo(u32 u) { return __uint_as_float(u << 16); }
__device__ __forceinline__ float b2f_hi(u32 u) { return __uint_as_float(u & 0xffff0000u); }
__device__ __forceinline__ u16 f2b(float f) {
    u32 u = __float_as_uint(f);
    return (u16)((u + 0x7fffu + ((u >> 16) & 1u)) >> 16);
}
__device__ __forceinline__ u32 pack2(float a, float b) {
    return (u32)f2b(a) | ((u32)f2b(b) << 16);
}

// ---------------------------------------------------------------- edge decode

__device__ __forceinline__ void load_edge(const int* ei, int e, int E, int i64,
                                          int& r, int& c) {
    if (i64) {
        const long long* p = (const long long*)ei;
        r = (int)p[e]; c = (int)p[E + e];
    } else {
        r = ei[e]; c = ei[E + e];
    }
}

__global__ void detect_i64_kernel(const int* ei, int n_check, int* flag) {
    __shared__ int any;
    if (threadIdx.x == 0) any = 0;
    __syncthreads();
    int local = 0;
    for (int i = threadIdx.x; i < n_check; i += blockDim.x)
        if (ei[2 * i + 1] != 0) local = 1;
    if (local) any = 1;  // benign race
    __syncthreads();
    if (threadIdx.x == 0) *flag = (any ? 0 : 1);  // 1 => int64 layout
}

// One packed 64b atomic per edge endpoint: (count << 40) | fixed-point weight sum.
// P_r[r]: out-degree sum + backward-CSR count; P_c[c]: in-degree sum + forward count.
__global__ void deg_hist_kernel(const int* __restrict__ ei, const int* __restrict__ flag,
                                const float* __restrict__ ew,
                                u64* P_r, u64* P_c, int E) {
    int e = blockIdx.x * blockDim.x + threadIdx.x;
    if (e >= E) return;
    int i64 = *flag;
    int r, c; load_edge(ei, e, E, i64, r, c);
    u64 v = (1ull << 40) | (u64)(ew[e] * DEG_SCALE);
    atomicAdd(&P_r[r], v);
    atomicAdd(&P_c[c], v);
}

// Exclusive scan of the two count fields (1 block, 1024 threads, serial chunks).
__global__ void scan_kernel(const u64* __restrict__ Pc, const u64* __restrict__ Pr,
                            int* of, int* ob, int* curf, int* curb, int N) {
    __shared__ int sf[1024], sb[1024];
    int t = threadIdx.x;
    int CH = (N + 1023) >> 10;
    int beg = t * CH, end = min(beg + CH, N);
    if (beg > N) beg = N;
    int sumf = 0, sumb = 0;
    for (int i = beg; i < end; ++i) { sumf += (int)(Pc[i] >> 40); sumb += (int)(Pr[i] >> 40); }
    sf[t] = sumf; sb[t] = sumb;
    __syncthreads();
    for (int d = 1; d < 1024; d <<= 1) {
        int xf = (t >= d) ? sf[t - d] : 0;
        int xb = (t >= d) ? sb[t - d] : 0;
        __syncthreads();
        sf[t] += xf; sb[t] += xb;
        __syncthreads();
    }
    int exf = sf[t] - sumf, exb = sb[t] - sumb;
    for (int i = beg; i < end; ++i) {
        of[i] = exf; curf[i] = exf; exf += (int)(Pc[i] >> 40);
        ob[i] = exb; curb[i] = exb; exb += (int)(Pr[i] >> 40);
    }
    if (t == 1023) { of[N] = exf; ob[N] = exb; }
}

// Fill CSR payloads as (src, coeff) pairs.
__global__ void scatter_kernel(const int* __restrict__ ei, const int* __restrict__ flag,
                               const float* __restrict__ ew,
                               const u64* __restrict__ P_r, const u64* __restrict__ P_c,
                               int* curf, int* curb, int2* pf, int2* pb, int E) {
    int e = blockIdx.x * blockDim.x + threadIdx.x;
    if (e >= E) return;
    int i64 = *flag;
    int r, c; load_edge(ei, e, E, i64, r, c);
    float w = ew[e];
    float deg_out = (float)(P_r[r] & MASK40) * DEG_INV;
    float deg_in  = (float)(P_c[c] & MASK40) * DEG_INV;
    int ipf = atomicAdd(&curf[c], 1);
    pf[ipf] = make_int2(r, __float_as_int(w / deg_out));
    int ipb = atomicAdd(&curb[r], 1);
    pb[ipb] = make_int2(c, __float_as_int(w / deg_in));
}

// XH = [X | H] in bf16. Each thread emits 8 bf16 (16B). N*12 chunks.
__global__ void build_xh_kernel(const float4* __restrict__ X4, const float4* __restrict__ H4,
                                uint4* __restrict__ XH, int N) {
    int idx = blockIdx.x * blockDim.x + threadIdx.x;
    if (idx >= N * 12) return;
    int n = idx / 12, c = idx % 12;
    float4 a, b;
    if (c < 4) { a = X4[n * 8 + c * 2]; b = X4[n * 8 + c * 2 + 1]; }
    else       { a = H4[n * 16 + (c - 4) * 2]; b = H4[n * 16 + (c - 4) * 2 + 1]; }
    uint4 o;
    o.x = pack2(a.x, a.y); o.y = pack2(a.z, a.w);
    o.z = pack2(b.x, b.y); o.w = pack2(b.z, b.w);
    XH[idx] = o;
}

// Dual-direction bf16 gather. blockDim = (12, 32): 12 lanes x 16B cover the 96-col row.
// out[n] = sum_e w[e] * x[src[e]]   (CHEBY: 2*sum - base[n]).
template <int CHEBY>
__global__ __launch_bounds__(384) void gather2_kernel(
    const uint4* __restrict__ xf, const uint4* __restrict__ xb,
    const int* __restrict__ offs_f, const int2* __restrict__ pf,
    const int* __restrict__ offs_b, const int2* __restrict__ pb,
    const uint4* __restrict__ base, uint4* __restrict__ outf, uint4* __restrict__ outb,
    int N) {
    const uint4* x; const int* offs; const int2* pr; uint4* out;
    if (blockIdx.y == 0) { x = xf; offs = offs_f; pr = pf; out = outf; }
    else                 { x = xb; offs = offs_b; pr = pb; out = outb; }
    int n = blockIdx.x * 32 + threadIdx.y;
    if (n >= N) return;
    int c = threadIdx.x;  // 0..11
    int s0 = offs[n], s1 = offs[n + 1];
    float a0 = 0, a1 = 0, a2 = 0, a3 = 0, a4 = 0, a5 = 0, a6 = 0, a7 = 0;
    int o = s0;
    for (; o + 2 <= s1; o += 2) {
        int2 p0 = pr[o], p1 = pr[o + 1];
        float w0 = __int_as_float(p0.y), w1 = __int_as_float(p1.y);
        uint4 v0 = x[(size_t)p0.x * 12 + c];
        uint4 v1 = x[(size_t)p1.x * 12 + c];
        a0 += w0 * b2f_lo(v0.x) + w1 * b2f_lo(v1.x);
        a1 += w0 * b2f_hi(v0.x) + w1 * b2f_hi(v1.x);
        a2 += w0 * b2f_lo(v0.y) + w1 * b2f_lo(v1.y);
        a3 += w0 * b2f_hi(v0.y) + w1 * b2f_hi(v1.y);
        a4 += w0 * b2f_lo(v0.z) + w1 * b2f_lo(v1.z);
        a5 += w0 * b2f_hi(v0.z) + w1 * b2f_hi(v1.z);
        a6 += w0 * b2f_lo(v0.w) + w1 * b2f_lo(v1.w);
        a7 += w0 * b2f_hi(v0.w) + w1 * b2f_hi(v1.w);
    }
    if (o < s1) {
        int2 p0 = pr[o];
        float w0 = __int_as_float(p0.y);
        uint4 v0 = x[(size_t)p0.x * 12 + c];
        a0 += w0 * b2f_lo(v0.x); a1 += w0 * b2f_hi(v0.x);
        a2 += w0 * b2f_lo(v0.y); a3 += w0 * b2f_hi(v0.y);
        a4 += w0 * b2f_lo(v0.z); a5 += w0 * b2f_hi(v0.z);
        a6 += w0 * b2f_lo(v0.w); a7 += w0 * b2f_hi(v0.w);
    }
    size_t oi = (size_t)n * 12 + c;
    if (CHEBY) {
        uint4 bv = base[oi];
        a0 = 2.f * a0 - b2f_lo(bv.x); a1 = 2.f * a1 - b2f_hi(bv.x);
        a2 = 2.f * a2 - b2f_lo(bv.y); a3 = 2.f * a3 - b2f_hi(bv.y);
        a4 = 2.f * a4 - b2f_lo(bv.z); a5 = 2.f * a5 - b2f_hi(bv.z);
        a6 = 2.f * a6 - b2f_lo(bv.w); a7 = 2.f * a7 - b2f_hi(bv.w);
    }
    uint4 ov;
    ov.x = pack2(a0, a1); ov.y = pack2(a2, a3);
    ov.z = pack2(a4, a5); ov.w = pack2(a6, a7);
    out[oi] = ov;
}

// Fuse + swizzle gate weights into MFMA-fragment-linear bf16:
// wf[kt][ct][lane][j]  = Wl[kt*32 + (lane>>4)*8 + j][ct*16 + (lane&15)]
// Wl = [480][64] with K segments {W00+W10, W01, W11, W02, W12}. grid.x = gate.
__global__ void prep_weights_kernel(const float* __restrict__ Wz, const float* __restrict__ Wr,
                                    const float* __restrict__ Wh, u16* __restrict__ wf_all) {
    const int KS = 96 * 64;
    int g = blockIdx.x;
    const float* W = (g == 0) ? Wz : (g == 1) ? Wr : Wh;
    u16* wf = wf_all + (size_t)g * 30720;
    for (int i = threadIdx.x; i < 30720; i += blockDim.x) {
        int j = i & 7, lane = (i >> 3) & 63, ct = (i >> 9) & 3, kt = i >> 11;
        int k = kt * 32 + (lane >> 4) * 8 + j;
        int col = ct * 16 + (lane & 15);
        int m = k / 96, fr = k - m * 96;
        int off = (m == 0) ? 0 : (m == 1) ? KS : (m == 2) ? 4 * KS : (m == 3) ? 2 * KS : 5 * KS;
        float v = W[off + fr * 64 + col];
        if (m == 0) v += W[3 * KS + fr * 64 + col];
        wf[i] = f2b(v);
    }
}

// MFMA GEMM: C[N,64] = sum_m A_m[N,96] @ W_m  (A bf16, W pre-swizzled bf16 in LDS).
// Block = 256 threads = 4 waves; block covers 64 rows; wave w covers rows [64b+16w, +16).
// MODE 0: Out = sigmoid(acc)              (Z gate, f32)
// MODE 1: XH[:,32:96] = H * sigmoid(acc)  (R gate, bf16, in place)
// MODE 2: Out = Z*H + (1-Z)*tanh(acc)     (H~ + GRU combine, f32)
template <int MODE>
__global__ __launch_bounds__(256) void gemm_mfma_kernel(
    const u16* __restrict__ A0, const u16* __restrict__ A1, const u16* __restrict__ A2,
    const u16* __restrict__ A3, const u16* __restrict__ A4,
    const u16* __restrict__ wfrag, const float* __restrict__ bias,
    const float* __restrict__ H, const float* __restrict__ Z,
    void* __restrict__ OutP, int N) {
    __shared__ u16 wl[30720];  // 61440 B -> 2 blocks/CU
    int t = threadIdx.x;
    {
        const uint4* src = (const uint4*)wfrag;
        uint4* dst = (uint4*)wl;
        for (int i = t; i < 3840; i += 256) dst[i] = src[i];
    }
    __syncthreads();

    int lane = t & 63, w = t >> 6;
    int rowBase = blockIdx.x * 64 + w * 16;
    int arow = rowBase + (lane & 15);
    size_t aoff = (size_t)arow * 96 + (lane >> 4) * 8;  // bf16 elements

    f32x4 acc[4];
#pragma unroll
    for (int ct = 0; ct < 4; ++ct) {
        float b = bias[ct * 16 + (lane & 15)];
        acc[ct] = (f32x4){b, b, b, b};
    }

    const u16* As[5] = {A0, A1, A2, A3, A4};
#pragma unroll
    for (int m = 0; m < 5; ++m) {
        const u16* Am = As[m];
#pragma unroll
        for (int k3 = 0; k3 < 3; ++k3) {
            short8 a = *(const short8*)(Am + aoff + k3 * 32);
            int ktg = m * 3 + k3;
#pragma unroll
            for (int ct = 0; ct < 4; ++ct) {
                short8 b = *(const short8*)(&wl[((ktg * 4 + ct) * 64 + lane) * 8]);
                acc[ct] = __builtin_amdgcn_mfma_f32_16x16x32_bf16(a, b, acc[ct], 0, 0, 0);
            }
        }
    }

    // Epilogue: lane covers col = ct*16 + (lane&15), rows (lane>>4)*4 + j.
    int rsub = (lane >> 4) * 4;
#pragma unroll
    for (int ct = 0; ct < 4; ++ct) {
        int col = ct * 16 + (lane & 15);
#pragma unroll
        for (int j = 0; j < 4; ++j) {
            int grow = rowBase + rsub + j;
            if (grow >= N) continue;
            float v = acc[ct][j];
            size_t bi = (size_t)grow * 64 + col;
            if (MODE == 0) {
                ((float*)OutP)[bi] = sigmoidf_(v);
            } else if (MODE == 1) {
                ((u16*)OutP)[(size_t)grow * 96 + 32 + col] = f2b(H[bi] * sigmoidf_(v));
            } else {
                float z = Z[bi];
                ((float*)OutP)[bi] = z * H[bi] + (1.f - z) * tanhf(v);
            }
        }
    }
}

// ---------------------------------------------------------------- launch

extern "C" void kernel_launch(void* const* d_in, const int* in_sizes, int n_in,
                              void* d_out, int out_size, void* d_ws, size_t ws_size,
                              hipStream_t stream) {
    const float* X  = (const float*)d_in[0];
    const int*   ei = (const int*)d_in[1];
    const float* ew = (const float*)d_in[2];
    const float* H  = (const float*)d_in[3];
    const float* Wz = (const float*)d_in[4];
    const float* bz = (const float*)d_in[5];
    const float* Wr = (const float*)d_in[6];
    const float* br = (const float*)d_in[7];
    const float* Wh = (const float*)d_in[8];
    const float* bh = (const float*)d_in[9];
    float* out = (float*)d_out;

    const int N = in_sizes[0] / 32;   // 50000
    const int E = in_sizes[2];        // 800000

    // ---- workspace carve (256B aligned) ----
    char* wp = (char*)d_ws;
    auto alloc = [&](size_t nbytes) -> void* {
        void* p = (void*)wp;
        wp += (nbytes + 255) & ~(size_t)255;
        return p;
    };
    u16* XH   = (u16*)alloc((size_t)N * 96 * 2);  // becomes XHR after R-GEMM
    u16* T1o  = (u16*)alloc((size_t)N * 96 * 2);
    u16* T1i  = (u16*)alloc((size_t)N * 96 * 2);
    u16* S2o  = (u16*)alloc((size_t)N * 96 * 2);
    u16* S2i  = (u16*)alloc((size_t)N * 96 * 2);
    float* AccZ = (float*)alloc((size_t)N * 64 * 4);
    u64* P_r  = (u64*)alloc((size_t)N * 8);
    u64* P_c  = (u64*)alloc((size_t)N * 8);
    int* offs_f = (int*)alloc((size_t)(N + 1) * 4);
    int* offs_b = (int*)alloc((size_t)(N + 1) * 4);
    int* cur_f  = (int*)alloc((size_t)N * 4);
    int* cur_b  = (int*)alloc((size_t)N * 4);
    int2* pair_f = (int2*)alloc((size_t)E * 8);
    int2* pair_b = (int2*)alloc((size_t)E * 8);
    u16* wf_all = (u16*)alloc((size_t)3 * 30720 * 2);
    int* flag   = (int*)alloc(256);

    const int eBlocks = (E + NTHREADS - 1) / NTHREADS;
    const int xhBlocks = (N * 12 + NTHREADS - 1) / NTHREADS;
    const int gemmBlocks = (N + 63) / 64;
    dim3 gatherBlock(12, 32);
    dim3 gatherGrid((N + 31) / 32, 2);

    // ---- edge preprocessing (shared by all three dconvs) ----
    hipMemsetAsync(P_r, 0, (size_t)N * 8, stream);
    hipMemsetAsync(P_c, 0, (size_t)N * 8, stream);

    detect_i64_kernel<<<1, 256, 0, stream>>>(ei, E < 8192 ? E : 8192, flag);
    prep_weights_kernel<<<3, 256, 0, stream>>>(Wz, Wr, Wh, wf_all);
    deg_hist_kernel<<<eBlocks, NTHREADS, 0, stream>>>(ei, flag, ew, P_r, P_c, E);
    scan_kernel<<<1, 1024, 0, stream>>>(P_c, P_r, offs_f, offs_b, cur_f, cur_b, N);
    scatter_kernel<<<eBlocks, NTHREADS, 0, stream>>>(ei, flag, ew, P_r, P_c,
                                                     cur_f, cur_b, pair_f, pair_b, E);

    // ---- phase ZR: shared T matrices on XH = [X|H] ----
    build_xh_kernel<<<xhBlocks, NTHREADS, 0, stream>>>((const float4*)X, (const float4*)H,
                                                       (uint4*)XH, N);
    gather2_kernel<0><<<gatherGrid, gatherBlock, 0, stream>>>(
        (const uint4*)XH, (const uint4*)XH, offs_f, pair_f, offs_b, pair_b,
        nullptr, (uint4*)T1o, (uint4*)T1i, N);
    gather2_kernel<1><<<gatherGrid, gatherBlock, 0, stream>>>(
        (const uint4*)T1o, (const uint4*)T1i, offs_f, pair_f, offs_b, pair_b,
        (const uint4*)XH, (uint4*)S2o, (uint4*)S2i, N);

    // Z gate (sigmoid fused), R gate (H*R written into XH in place -> XHR)
    gemm_mfma_kernel<0><<<gemmBlocks, 256, 0, stream>>>(
        XH, T1o, T1i, S2o, S2i, wf_all, bz, nullptr, nullptr, AccZ, N);
    gemm_mfma_kernel<1><<<gemmBlocks, 256, 0, stream>>>(
        XH, T1o, T1i, S2o, S2i, wf_all + 30720, br, H, nullptr, XH, N);

    // ---- phase H: propagate XHR ----
    gather2_kernel<0><<<gatherGrid, gatherBlock, 0, stream>>>(
        (const uint4*)XH, (const uint4*)XH, offs_f, pair_f, offs_b, pair_b,
        nullptr, (uint4*)T1o, (uint4*)T1i, N);
    gather2_kernel<1><<<gatherGrid, gatherBlock, 0, stream>>>(
        (const uint4*)T1o, (const uint4*)T1i, offs_f, pair_f, offs_b, pair_b,
        (const uint4*)XH, (uint4*)S2o, (uint4*)S2i, N);

    // H~ gate + GRU combine fused
    gemm_mfma_kernel<2><<<gemmBlocks, 256, 0, stream>>>(
        XH, T1o, T1i, S2o, S2i, wf_all + 2 * 30720, bh, H, AccZ, out, N);
}

// Round 4
// 480.214 us; speedup vs baseline: 3.4025x; 1.4971x over previous
//
#include <hip/hip_runtime.h>

// DCRNN cell: 3x diffusion conv (fwd/bwd, K=3 Chebyshev) + GRU gating.
// N=50000 nodes, E=800000 edges, F_IN=32, F_OUT=64, fan=96.
// Round 4: multi-block decoupled scan (round-3's single-block scan was 253us).

#define NTHREADS 256

typedef unsigned short u16;
typedef unsigned int u32;
typedef unsigned long long u64;
typedef __attribute__((ext_vector_type(8))) short short8;   // 8 bf16 (4 VGPRs)
typedef __attribute__((ext_vector_type(4))) float f32x4;

#define DEG_SCALE 268435456.0f          // 2^28
#define DEG_INV   3.725290298461914e-9f // 2^-28
#define MASK40    ((1ull << 40) - 1)

__device__ __forceinline__ float sigmoidf_(float x) { return 1.f / (1.f + __expf(-x)); }
__device__ __forceinline__ float b2f_lo(u32 u) { return __uint_as_float(u << 16); }
__device__ __forceinline__ float b2f_hi(u32 u) { return __uint_as_float(u & 0xffff0000u); }
__device__ __forceinline__ u16 f2b(float f) {
    u32 u = __float_as_uint(f);
    return (u16)((u + 0x7fffu + ((u >> 16) & 1u)) >> 16);
}
__device__ __forceinline__ u32 pack2(float a, float b) {
    return (u32)f2b(a) | ((u32)f2b(b) << 16);
}

// ---------------------------------------------------------------- edge decode

__device__ __forceinline__ void load_edge(const int* ei, int e, int E, int i64,
                                          int& r, int& c) {
    if (i64) {
        const long long* p = (const long long*)ei;
        r = (int)p[e]; c = (int)p[E + e];
    } else {
        r = ei[e]; c = ei[E + e];
    }
}

__global__ void detect_i64_kernel(const int* ei, int n_check, int* flag) {
    __shared__ int any;
    if (threadIdx.x == 0) any = 0;
    __syncthreads();
    int local = 0;
    for (int i = threadIdx.x; i < n_check; i += blockDim.x)
        if (ei[2 * i + 1] != 0) local = 1;
    if (local) any = 1;  // benign race
    __syncthreads();
    if (threadIdx.x == 0) *flag = (any ? 0 : 1);  // 1 => int64 layout
}

// One packed 64b atomic per edge endpoint: (count << 40) | fixed-point weight sum.
// P_r[r]: out-degree sum + backward-CSR count; P_c[c]: in-degree sum + forward count.
__global__ void deg_hist_kernel(const int* __restrict__ ei, const int* __restrict__ flag,
                                const float* __restrict__ ew,
                                u64* P_r, u64* P_c, int E) {
    int e = blockIdx.x * blockDim.x + threadIdx.x;
    if (e >= E) return;
    int i64 = *flag;
    int r, c; load_edge(ei, e, E, i64, r, c);
    u64 v = (1ull << 40) | (u64)(ew[e] * DEG_SCALE);
    atomicAdd(&P_r[r], v);
    atomicAdd(&P_c[c], v);
}

// ---- 3-phase decoupled scan of the two count fields ----
__global__ void blocksum_kernel(const u64* __restrict__ Pc, const u64* __restrict__ Pr,
                                int* bsf, int* bsb, int N) {
    __shared__ int sf[256], sb[256];
    int t = threadIdx.x;
    int i = blockIdx.x * 256 + t;
    int vf = 0, vb = 0;
    if (i < N) { vf = (int)(Pc[i] >> 40); vb = (int)(Pr[i] >> 40); }
    sf[t] = vf; sb[t] = vb;
    __syncthreads();
    for (int d = 128; d > 0; d >>= 1) {
        if (t < d) { sf[t] += sf[t + d]; sb[t] += sb[t + d]; }
        __syncthreads();
    }
    if (t == 0) { bsf[blockIdx.x] = sf[0]; bsb[blockIdx.x] = sb[0]; }
}

// Exclusive-scan the (<=1024) block sums in place; write array totals (=E).
__global__ void scansums_kernel(int* bsf, int* bsb, int* of, int* ob, int nb, int N, int E) {
    __shared__ int sf[1024], sb[1024];
    int t = threadIdx.x;
    int vf = (t < nb) ? bsf[t] : 0;
    int vb = (t < nb) ? bsb[t] : 0;
    sf[t] = vf; sb[t] = vb;
    __syncthreads();
    for (int d = 1; d < 1024; d <<= 1) {
        int xf = (t >= d) ? sf[t - d] : 0;
        int xb = (t >= d) ? sb[t - d] : 0;
        __syncthreads();
        sf[t] += xf; sb[t] += xb;
        __syncthreads();
    }
    if (t < nb) { bsf[t] = sf[t] - vf; bsb[t] = sb[t] - vb; }  // exclusive
    if (t == 0) { of[N] = E; ob[N] = E; }
}

__global__ void writeoffs_kernel(const u64* __restrict__ Pc, const u64* __restrict__ Pr,
                                 const int* __restrict__ bsf, const int* __restrict__ bsb,
                                 int* of, int* ob, int* curf, int* curb, int N) {
    __shared__ int sf[256], sb[256];
    int t = threadIdx.x;
    int i = blockIdx.x * 256 + t;
    int vf = 0, vb = 0;
    if (i < N) { vf = (int)(Pc[i] >> 40); vb = (int)(Pr[i] >> 40); }
    sf[t] = vf; sb[t] = vb;
    __syncthreads();
    for (int d = 1; d < 256; d <<= 1) {
        int xf = (t >= d) ? sf[t - d] : 0;
        int xb = (t >= d) ? sb[t - d] : 0;
        __syncthreads();
        sf[t] += xf; sb[t] += xb;
        __syncthreads();
    }
    if (i < N) {
        int ef = bsf[blockIdx.x] + sf[t] - vf;
        int eb = bsb[blockIdx.x] + sb[t] - vb;
        of[i] = ef; curf[i] = ef;
        ob[i] = eb; curb[i] = eb;
    }
}

// Fill CSR payloads as (src, coeff) pairs.
__global__ void scatter_kernel(const int* __restrict__ ei, const int* __restrict__ flag,
                               const float* __restrict__ ew,
                               const u64* __restrict__ P_r, const u64* __restrict__ P_c,
                               int* curf, int* curb, int2* pf, int2* pb, int E) {
    int e = blockIdx.x * blockDim.x + threadIdx.x;
    if (e >= E) return;
    int i64 = *flag;
    int r, c; load_edge(ei, e, E, i64, r, c);
    float w = ew[e];
    float deg_out = (float)(P_r[r] & MASK40) * DEG_INV;
    float deg_in  = (float)(P_c[c] & MASK40) * DEG_INV;
    int ipf = atomicAdd(&curf[c], 1);
    pf[ipf] = make_int2(r, __float_as_int(w / deg_out));
    int ipb = atomicAdd(&curb[r], 1);
    pb[ipb] = make_int2(c, __float_as_int(w / deg_in));
}

// XH = [X | H] in bf16. Each thread emits 8 bf16 (16B). N*12 chunks.
__global__ void build_xh_kernel(const float4* __restrict__ X4, const float4* __restrict__ H4,
                                uint4* __restrict__ XH, int N) {
    int idx = blockIdx.x * blockDim.x + threadIdx.x;
    if (idx >= N * 12) return;
    int n = idx / 12, c = idx % 12;
    float4 a, b;
    if (c < 4) { a = X4[n * 8 + c * 2]; b = X4[n * 8 + c * 2 + 1]; }
    else       { a = H4[n * 16 + (c - 4) * 2]; b = H4[n * 16 + (c - 4) * 2 + 1]; }
    uint4 o;
    o.x = pack2(a.x, a.y); o.y = pack2(a.z, a.w);
    o.z = pack2(b.x, b.y); o.w = pack2(b.z, b.w);
    XH[idx] = o;
}

// Dual-direction bf16 gather. blockDim = (12, 32): 12 lanes x 16B cover the 96-col row.
// out[n] = sum_e w[e] * x[src[e]]   (CHEBY: 2*sum - base[n]).
template <int CHEBY>
__global__ __launch_bounds__(384) void gather2_kernel(
    const uint4* __restrict__ xf, const uint4* __restrict__ xb,
    const int* __restrict__ offs_f, const int2* __restrict__ pf,
    const int* __restrict__ offs_b, const int2* __restrict__ pb,
    const uint4* __restrict__ base, uint4* __restrict__ outf, uint4* __restrict__ outb,
    int N) {
    const uint4* x; const int* offs; const int2* pr; uint4* out;
    if (blockIdx.y == 0) { x = xf; offs = offs_f; pr = pf; out = outf; }
    else                 { x = xb; offs = offs_b; pr = pb; out = outb; }
    int n = blockIdx.x * 32 + threadIdx.y;
    if (n >= N) return;
    int c = threadIdx.x;  // 0..11
    int s0 = offs[n], s1 = offs[n + 1];
    float a0 = 0, a1 = 0, a2 = 0, a3 = 0, a4 = 0, a5 = 0, a6 = 0, a7 = 0;
    int o = s0;
    for (; o + 2 <= s1; o += 2) {
        int2 p0 = pr[o], p1 = pr[o + 1];
        float w0 = __int_as_float(p0.y), w1 = __int_as_float(p1.y);
        uint4 v0 = x[(size_t)p0.x * 12 + c];
        uint4 v1 = x[(size_t)p1.x * 12 + c];
        a0 += w0 * b2f_lo(v0.x) + w1 * b2f_lo(v1.x);
        a1 += w0 * b2f_hi(v0.x) + w1 * b2f_hi(v1.x);
        a2 += w0 * b2f_lo(v0.y) + w1 * b2f_lo(v1.y);
        a3 += w0 * b2f_hi(v0.y) + w1 * b2f_hi(v1.y);
        a4 += w0 * b2f_lo(v0.z) + w1 * b2f_lo(v1.z);
        a5 += w0 * b2f_hi(v0.z) + w1 * b2f_hi(v1.z);
        a6 += w0 * b2f_lo(v0.w) + w1 * b2f_lo(v1.w);
        a7 += w0 * b2f_hi(v0.w) + w1 * b2f_hi(v1.w);
    }
    if (o < s1) {
        int2 p0 = pr[o];
        float w0 = __int_as_float(p0.y);
        uint4 v0 = x[(size_t)p0.x * 12 + c];
        a0 += w0 * b2f_lo(v0.x); a1 += w0 * b2f_hi(v0.x);
        a2 += w0 * b2f_lo(v0.y); a3 += w0 * b2f_hi(v0.y);
        a4 += w0 * b2f_lo(v0.z); a5 += w0 * b2f_hi(v0.z);
        a6 += w0 * b2f_lo(v0.w); a7 += w0 * b2f_hi(v0.w);
    }
    size_t oi = (size_t)n * 12 + c;
    if (CHEBY) {
        uint4 bv = base[oi];
        a0 = 2.f * a0 - b2f_lo(bv.x); a1 = 2.f * a1 - b2f_hi(bv.x);
        a2 = 2.f * a2 - b2f_lo(bv.y); a3 = 2.f * a3 - b2f_hi(bv.y);
        a4 = 2.f * a4 - b2f_lo(bv.z); a5 = 2.f * a5 - b2f_hi(bv.z);
        a6 = 2.f * a6 - b2f_lo(bv.w); a7 = 2.f * a7 - b2f_hi(bv.w);
    }
    uint4 ov;
    ov.x = pack2(a0, a1); ov.y = pack2(a2, a3);
    ov.z = pack2(a4, a5); ov.w = pack2(a6, a7);
    out[oi] = ov;
}

// Fuse + swizzle gate weights into MFMA-fragment-linear bf16:
// wf[kt][ct][lane][j]  = Wl[kt*32 + (lane>>4)*8 + j][ct*16 + (lane&15)]
// Wl = [480][64] with K segments {W00+W10, W01, W11, W02, W12}. grid.x = gate.
__global__ void prep_weights_kernel(const float* __restrict__ Wz, const float* __restrict__ Wr,
                                    const float* __restrict__ Wh, u16* __restrict__ wf_all) {
    const int KS = 96 * 64;
    int g = blockIdx.x;
    const float* W = (g == 0) ? Wz : (g == 1) ? Wr : Wh;
    u16* wf = wf_all + (size_t)g * 30720;
    for (int i = threadIdx.x; i < 30720; i += blockDim.x) {
        int j = i & 7, lane = (i >> 3) & 63, ct = (i >> 9) & 3, kt = i >> 11;
        int k = kt * 32 + (lane >> 4) * 8 + j;
        int col = ct * 16 + (lane & 15);
        int m = k / 96, fr = k - m * 96;
        int off = (m == 0) ? 0 : (m == 1) ? KS : (m == 2) ? 4 * KS : (m == 3) ? 2 * KS : 5 * KS;
        float v = W[off + fr * 64 + col];
        if (m == 0) v += W[3 * KS + fr * 64 + col];
        wf[i] = f2b(v);
    }
}

// MFMA GEMM: C[N,64] = sum_m A_m[N,96] @ W_m  (A bf16, W pre-swizzled bf16 in LDS).
// Block = 256 threads = 4 waves; block covers 64 rows; wave w covers rows [64b+16w, +16).
// MODE 0: Out = sigmoid(acc)              (Z gate, f32)
// MODE 1: XH[:,32:96] = H * sigmoid(acc)  (R gate, bf16, in place)
// MODE 2: Out = Z*H + (1-Z)*tanh(acc)     (H~ + GRU combine, f32)
template <int MODE>
__global__ __launch_bounds__(256) void gemm_mfma_kernel(
    const u16* __restrict__ A0, const u16* __restrict__ A1, const u16* __restrict__ A2,
    const u16* __restrict__ A3, const u16* __restrict__ A4,
    const u16* __restrict__ wfrag, const float* __restrict__ bias,
    const float* __restrict__ H, const float* __restrict__ Z,
    void* __restrict__ OutP, int N) {
    __shared__ u16 wl[30720];  // 61440 B -> 2 blocks/CU
    int t = threadIdx.x;
    {
        const uint4* src = (const uint4*)wfrag;
        uint4* dst = (uint4*)wl;
        for (int i = t; i < 3840; i += 256) dst[i] = src[i];
    }
    __syncthreads();

    int lane = t & 63, w = t >> 6;
    int rowBase = blockIdx.x * 64 + w * 16;
    int arow = rowBase + (lane & 15);
    size_t aoff = (size_t)arow * 96 + (lane >> 4) * 8;  // bf16 elements

    f32x4 acc[4];
#pragma unroll
    for (int ct = 0; ct < 4; ++ct) {
        float b = bias[ct * 16 + (lane & 15)];
        acc[ct] = (f32x4){b, b, b, b};
    }

    const u16* As[5] = {A0, A1, A2, A3, A4};
#pragma unroll
    for (int m = 0; m < 5; ++m) {
        const u16* Am = As[m];
#pragma unroll
        for (int k3 = 0; k3 < 3; ++k3) {
            short8 a = *(const short8*)(Am + aoff + k3 * 32);
            int ktg = m * 3 + k3;
#pragma unroll
            for (int ct = 0; ct < 4; ++ct) {
                short8 b = *(const short8*)(&wl[((ktg * 4 + ct) * 64 + lane) * 8]);
                acc[ct] = __builtin_amdgcn_mfma_f32_16x16x32_bf16(a, b, acc[ct], 0, 0, 0);
            }
        }
    }

    // Epilogue: lane covers col = ct*16 + (lane&15), rows (lane>>4)*4 + j.
    int rsub = (lane >> 4) * 4;
#pragma unroll
    for (int ct = 0; ct < 4; ++ct) {
        int col = ct * 16 + (lane & 15);
#pragma unroll
        for (int j = 0; j < 4; ++j) {
            int grow = rowBase + rsub + j;
            if (grow >= N) continue;
            float v = acc[ct][j];
            size_t bi = (size_t)grow * 64 + col;
            if (MODE == 0) {
                ((float*)OutP)[bi] = sigmoidf_(v);
            } else if (MODE == 1) {
                ((u16*)OutP)[(size_t)grow * 96 + 32 + col] = f2b(H[bi] * sigmoidf_(v));
            } else {
                float z = Z[bi];
                ((float*)OutP)[bi] = z * H[bi] + (1.f - z) * tanhf(v);
            }
        }
    }
}

// ---------------------------------------------------------------- launch

extern "C" void kernel_launch(void* const* d_in, const int* in_sizes, int n_in,
                              void* d_out, int out_size, void* d_ws, size_t ws_size,
                              hipStream_t stream) {
    const float* X  = (const float*)d_in[0];
    const int*   ei = (const int*)d_in[1];
    const float* ew = (const float*)d_in[2];
    const float* H  = (const float*)d_in[3];
    const float* Wz = (const float*)d_in[4];
    const float* bz = (const float*)d_in[5];
    const float* Wr = (const float*)d_in[6];
    const float* br = (const float*)d_in[7];
    const float* Wh = (const float*)d_in[8];
    const float* bh = (const float*)d_in[9];
    float* out = (float*)d_out;

    const int N = in_sizes[0] / 32;   // 50000
    const int E = in_sizes[2];        // 800000

    // ---- workspace carve (256B aligned) ----
    char* wp = (char*)d_ws;
    auto alloc = [&](size_t nbytes) -> void* {
        void* p = (void*)wp;
        wp += (nbytes + 255) & ~(size_t)255;
        return p;
    };
    u16* XH   = (u16*)alloc((size_t)N * 96 * 2);  // becomes XHR after R-GEMM
    u16* T1o  = (u16*)alloc((size_t)N * 96 * 2);
    u16* T1i  = (u16*)alloc((size_t)N * 96 * 2);
    u16* S2o  = (u16*)alloc((size_t)N * 96 * 2);
    u16* S2i  = (u16*)alloc((size_t)N * 96 * 2);
    float* AccZ = (float*)alloc((size_t)N * 64 * 4);
    u64* P_r  = (u64*)alloc((size_t)N * 8);
    u64* P_c  = (u64*)alloc((size_t)N * 8);
    int* offs_f = (int*)alloc((size_t)(N + 1) * 4);
    int* offs_b = (int*)alloc((size_t)(N + 1) * 4);
    int* cur_f  = (int*)alloc((size_t)N * 4);
    int* cur_b  = (int*)alloc((size_t)N * 4);
    int2* pair_f = (int2*)alloc((size_t)E * 8);
    int2* pair_b = (int2*)alloc((size_t)E * 8);
    u16* wf_all = (u16*)alloc((size_t)3 * 30720 * 2);
    int* bs_f = (int*)alloc(1024 * 4);
    int* bs_b = (int*)alloc(1024 * 4);
    int* flag   = (int*)alloc(256);

    const int eBlocks = (E + NTHREADS - 1) / NTHREADS;
    const int xhBlocks = (N * 12 + NTHREADS - 1) / NTHREADS;
    const int gemmBlocks = (N + 63) / 64;
    const int scanBlocks = (N + 255) / 256;   // 196 <= 1024
    dim3 gatherBlock(12, 32);
    dim3 gatherGrid((N + 31) / 32, 2);

    // ---- edge preprocessing (shared by all three dconvs) ----
    hipMemsetAsync(P_r, 0, (size_t)N * 8, stream);
    hipMemsetAsync(P_c, 0, (size_t)N * 8, stream);

    detect_i64_kernel<<<1, 256, 0, stream>>>(ei, E < 8192 ? E : 8192, flag);
    prep_weights_kernel<<<3, 256, 0, stream>>>(Wz, Wr, Wh, wf_all);
    deg_hist_kernel<<<eBlocks, NTHREADS, 0, stream>>>(ei, flag, ew, P_r, P_c, E);
    blocksum_kernel<<<scanBlocks, 256, 0, stream>>>(P_c, P_r, bs_f, bs_b, N);
    scansums_kernel<<<1, 1024, 0, stream>>>(bs_f, bs_b, offs_f, offs_b, scanBlocks, N, E);
    writeoffs_kernel<<<scanBlocks, 256, 0, stream>>>(P_c, P_r, bs_f, bs_b,
                                                     offs_f, offs_b, cur_f, cur_b, N);
    scatter_kernel<<<eBlocks, NTHREADS, 0, stream>>>(ei, flag, ew, P_r, P_c,
                                                     cur_f, cur_b, pair_f, pair_b, E);

    // ---- phase ZR: shared T matrices on XH = [X|H] ----
    build_xh_kernel<<<xhBlocks, NTHREADS, 0, stream>>>((const float4*)X, (const float4*)H,
                                                       (uint4*)XH, N);
    gather2_kernel<0><<<gatherGrid, gatherBlock, 0, stream>>>(
        (const uint4*)XH, (const uint4*)XH, offs_f, pair_f, offs_b, pair_b,
        nullptr, (uint4*)T1o, (uint4*)T1i, N);
    gather2_kernel<1><<<gatherGrid, gatherBlock, 0, stream>>>(
        (const uint4*)T1o, (const uint4*)T1i, offs_f, pair_f, offs_b, pair_b,
        (const uint4*)XH, (uint4*)S2o, (uint4*)S2i, N);

    // Z gate (sigmoid fused), R gate (H*R written into XH in place -> XHR)
    gemm_mfma_kernel<0><<<gemmBlocks, 256, 0, stream>>>(
        XH, T1o, T1i, S2o, S2i, wf_all, bz, nullptr, nullptr, AccZ, N);
    gemm_mfma_kernel<1><<<gemmBlocks, 256, 0, stream>>>(
        XH, T1o, T1i, S2o, S2i, wf_all + 30720, br, H, nullptr, XH, N);

    // ---- phase H: propagate XHR ----
    gather2_kernel<0><<<gatherGrid, gatherBlock, 0, stream>>>(
        (const uint4*)XH, (const uint4*)XH, offs_f, pair_f, offs_b, pair_b,
        nullptr, (uint4*)T1o, (uint4*)T1i, N);
    gather2_kernel<1><<<gatherGrid, gatherBlock, 0, stream>>>(
        (const uint4*)T1o, (const uint4*)T1i, offs_f, pair_f, offs_b, pair_b,
        (const uint4*)XH, (uint4*)S2o, (uint4*)S2i, N);

    // H~ gate + GRU combine fused
    gemm_mfma_kernel<2><<<gemmBlocks, 256, 0, stream>>>(
        XH, T1o, T1i, S2o, S2i, wf_all + 2 * 30720, bh, H, AccZ, out, N);
}

// Round 5
// 382.548 us; speedup vs baseline: 4.2711x; 1.2553x over previous
//
#include <hip/hip_runtime.h>

// DCRNN cell: 3x diffusion conv (fwd/bwd, K=3 Chebyshev) + GRU gating.
// N=50000 nodes, E=800000 edges, F_IN=32, F_OUT=64, fan=96.
// Round 5: bucketed CSR build (LDS-local degrees/cursors) replaces global
// atomic deg_hist + scatter (write amplification 98MB -> ~payload).

#define NTHREADS 256
#define BKT_BITS 10
#define BKT_NODES 1024
#define STG_CAP 32768   // per-bucket staging capacity (expected ~16.4K, sigma ~130)

typedef unsigned short u16;
typedef unsigned int u32;
typedef unsigned long long u64;
typedef __attribute__((ext_vector_type(8))) short short8;   // 8 bf16 (4 VGPRs)
typedef __attribute__((ext_vector_type(4))) float f32x4;

__device__ __forceinline__ float sigmoidf_(float x) { return 1.f / (1.f + __expf(-x)); }
__device__ __forceinline__ float b2f_lo(u32 u) { return __uint_as_float(u << 16); }
__device__ __forceinline__ float b2f_hi(u32 u) { return __uint_as_float(u & 0xffff0000u); }
__device__ __forceinline__ u16 f2b(float f) {
    u32 u = __float_as_uint(f);
    return (u16)((u + 0x7fffu + ((u >> 16) & 1u)) >> 16);
}
__device__ __forceinline__ u32 pack2(float a, float b) {
    return (u32)f2b(a) | ((u32)f2b(b) << 16);
}

// ---------------------------------------------------------------- edge decode

__device__ __forceinline__ void load_edge(const int* ei, int e, int E, int i64,
                                          int& r, int& c) {
    if (i64) {
        const long long* p = (const long long*)ei;
        r = (int)p[e]; c = (int)p[E + e];
    } else {
        r = ei[e]; c = ei[E + e];
    }
}

__global__ void detect_i64_kernel(const int* ei, int n_check, int* flag) {
    __shared__ int any;
    if (threadIdx.x == 0) any = 0;
    __syncthreads();
    int local = 0;
    for (int i = threadIdx.x; i < n_check; i += blockDim.x)
        if (ei[2 * i + 1] != 0) local = 1;
    if (local) any = 1;  // benign race
    __syncthreads();
    if (threadIdx.x == 0) *flag = (any ? 0 : 1);  // 1 => int64 layout
}

// ---- Pass 1: bin edges into node-range buckets (both directions). ----
// Staged entry: {w_bits, (src<<10)|dst_local}  (src < 65536 fits 16b; dst_local 10b)
__global__ __launch_bounds__(1024) void bin_kernel(
    const int* __restrict__ ei, const int* __restrict__ flag, const float* __restrict__ ew,
    int* gCntF, int* gCntB, uint2* __restrict__ stgF, uint2* __restrict__ stgB,
    int E, int NB) {
    __shared__ int cF[64], cB[64], bF[64], bB[64];
    int t = threadIdx.x;
    if (t < NB) { cF[t] = 0; cB[t] = 0; }
    __syncthreads();
    int i64 = *flag;
    int r[4], c[4], e[4]; float w[4];
#pragma unroll
    for (int k = 0; k < 4; ++k) {
        e[k] = blockIdx.x * 4096 + k * 1024 + t;
        if (e[k] < E) {
            load_edge(ei, e[k], E, i64, r[k], c[k]);
            w[k] = ew[e[k]];
            atomicAdd(&cF[c[k] >> BKT_BITS], 1);
            atomicAdd(&cB[r[k] >> BKT_BITS], 1);
        }
    }
    __syncthreads();
    if (t < NB) bF[t] = atomicAdd(&gCntF[t], cF[t]);
    if (t >= 256 && t < 256 + NB) bB[t - 256] = atomicAdd(&gCntB[t - 256], cB[t - 256]);
    __syncthreads();
    if (t < NB) cF[t] = 0;                      // reuse as intra-block cursor
    if (t >= 256 && t < 256 + NB) cB[t - 256] = 0;
    __syncthreads();
#pragma unroll
    for (int k = 0; k < 4; ++k) {
        if (e[k] < E) {
            int jf = c[k] >> BKT_BITS;
            int pf = bF[jf] + atomicAdd(&cF[jf], 1);
            stgF[(size_t)jf * STG_CAP + pf] =
                make_uint2(__float_as_uint(w[k]), ((u32)r[k] << BKT_BITS) | (u32)(c[k] & (BKT_NODES - 1)));
            int jb = r[k] >> BKT_BITS;
            int pb = bB[jb] + atomicAdd(&cB[jb], 1);
            stgB[(size_t)jb * STG_CAP + pb] =
                make_uint2(__float_as_uint(w[k]), ((u32)c[k] << BKT_BITS) | (u32)(r[k] & (BKT_NODES - 1)));
        }
    }
}

// ---- tiny scan over bucket totals -> CSR region bases ----
__global__ void bktscan_kernel(const int* __restrict__ gCntF, const int* __restrict__ gCntB,
                               int* bBaseF, int* bBaseB, int* of, int* ob,
                               int NB, int N, int E) {
    if (threadIdx.x == 0) {
        int s = 0;
        for (int j = 0; j < NB; ++j) { bBaseF[j] = s; s += gCntF[j]; }
        bBaseF[NB] = s; of[N] = E;
    }
    if (threadIdx.x == 1) {
        int s = 0;
        for (int j = 0; j < NB; ++j) { bBaseB[j] = s; s += gCntB[j]; }
        bBaseB[NB] = s; ob[N] = E;
    }
}

// ---- Pass 2a: weighted degrees per bucket, accumulated in LDS. ----
// fwd bucket (grouped by dst=col) -> deg_in; bwd bucket -> deg_out.
__global__ __launch_bounds__(1024) void bktdeg_kernel(
    const uint2* __restrict__ stgF, const uint2* __restrict__ stgB,
    const int* __restrict__ gCntF, const int* __restrict__ gCntB,
    float* __restrict__ deg_in, float* __restrict__ deg_out, int N, int NB) {
    __shared__ float acc[BKT_NODES];
    int j = blockIdx.x, t = threadIdx.x;
    bool fwd = j < NB;
    int jb = fwd ? j : j - NB;
    acc[t] = 0.f;
    __syncthreads();
    const uint2* stg = (fwd ? stgF : stgB) + (size_t)jb * STG_CAP;
    int m = fwd ? gCntF[jb] : gCntB[jb];
    for (int i = t; i < m; i += 1024) {
        uint2 p = stg[i];
        atomicAdd(&acc[p.y & (BKT_NODES - 1)], __uint_as_float(p.x));
    }
    __syncthreads();
    int n = jb * BKT_NODES + t;
    if (n < N) { if (fwd) deg_in[n] = acc[t]; else deg_out[n] = acc[t]; }
}

// ---- Pass 2b: per-node offs + exact CSR payload (src, coeff). ----
// One block owns one bucket; positions via LDS cursors; writes stay L2-local.
__global__ __launch_bounds__(1024) void bktcsr_kernel(
    const uint2* __restrict__ stgF, const uint2* __restrict__ stgB,
    const int* __restrict__ gCntF, const int* __restrict__ gCntB,
    const int* __restrict__ bBaseF, const int* __restrict__ bBaseB,
    const float* __restrict__ deg_in, const float* __restrict__ deg_out,
    int* __restrict__ of, int* __restrict__ ob,
    int2* __restrict__ pf, int2* __restrict__ pb, int N, int NB) {
    __shared__ int cnt[BKT_NODES], scn[BKT_NODES];
    int j = blockIdx.x, t = threadIdx.x;
    bool fwd = j < NB;
    int jb = fwd ? j : j - NB;
    const uint2* stg = (fwd ? stgF : stgB) + (size_t)jb * STG_CAP;
    int m = fwd ? gCntF[jb] : gCntB[jb];
    int base = fwd ? bBaseF[jb] : bBaseB[jb];
    const float* degS = fwd ? deg_out : deg_in;  // coeff divides by SRC-side degree
    cnt[t] = 0;
    __syncthreads();
    for (int i = t; i < m; i += 1024) atomicAdd(&cnt[stg[i].y & (BKT_NODES - 1)], 1);
    __syncthreads();
    int v = cnt[t];
    scn[t] = v;
    __syncthreads();
    for (int d = 1; d < 1024; d <<= 1) {
        int x = (t >= d) ? scn[t - d] : 0;
        __syncthreads();
        scn[t] += x;
        __syncthreads();
    }
    int ex = scn[t] - v;
    int n = jb * BKT_NODES + t;
    if (n < N) { if (fwd) of[n] = base + ex; else ob[n] = base + ex; }
    cnt[t] = ex;  // reuse as cursor
    __syncthreads();
    for (int i = t; i < m; i += 1024) {
        uint2 p = stg[i];
        int dl = p.y & (BKT_NODES - 1);
        int src = p.y >> BKT_BITS;
        float coeff = __uint_as_float(p.x) / degS[src];
        int pos = base + atomicAdd(&cnt[dl], 1);
        int2 pr = make_int2(src, __float_as_int(coeff));
        if (fwd) pf[pos] = pr; else pb[pos] = pr;
    }
}

// XH = [X | H] in bf16. Each thread emits 8 bf16 (16B). N*12 chunks.
__global__ void build_xh_kernel(const float4* __restrict__ X4, const float4* __restrict__ H4,
                                uint4* __restrict__ XH, int N) {
    int idx = blockIdx.x * blockDim.x + threadIdx.x;
    if (idx >= N * 12) return;
    int n = idx / 12, c = idx % 12;
    float4 a, b;
    if (c < 4) { a = X4[n * 8 + c * 2]; b = X4[n * 8 + c * 2 + 1]; }
    else       { a = H4[n * 16 + (c - 4) * 2]; b = H4[n * 16 + (c - 4) * 2 + 1]; }
    uint4 o;
    o.x = pack2(a.x, a.y); o.y = pack2(a.z, a.w);
    o.z = pack2(b.x, b.y); o.w = pack2(b.z, b.w);
    XH[idx] = o;
}

// Dual-direction bf16 gather. blockDim = (12, 32): 12 lanes x 16B cover the 96-col row.
// out[n] = sum_e w[e] * x[src[e]]   (CHEBY: 2*sum - base[n]).
template <int CHEBY>
__global__ __launch_bounds__(384) void gather2_kernel(
    const uint4* __restrict__ xf, const uint4* __restrict__ xb,
    const int* __restrict__ offs_f, const int2* __restrict__ pf,
    const int* __restrict__ offs_b, const int2* __restrict__ pb,
    const uint4* __restrict__ base, uint4* __restrict__ outf, uint4* __restrict__ outb,
    int N) {
    const uint4* x; const int* offs; const int2* pr; uint4* out;
    if (blockIdx.y == 0) { x = xf; offs = offs_f; pr = pf; out = outf; }
    else                 { x = xb; offs = offs_b; pr = pb; out = outb; }
    int n = blockIdx.x * 32 + threadIdx.y;
    if (n >= N) return;
    int c = threadIdx.x;  // 0..11
    int s0 = offs[n], s1 = offs[n + 1];
    float a0 = 0, a1 = 0, a2 = 0, a3 = 0, a4 = 0, a5 = 0, a6 = 0, a7 = 0;
    int o = s0;
    for (; o + 2 <= s1; o += 2) {
        int2 p0 = pr[o], p1 = pr[o + 1];
        float w0 = __int_as_float(p0.y), w1 = __int_as_float(p1.y);
        uint4 v0 = x[(size_t)p0.x * 12 + c];
        uint4 v1 = x[(size_t)p1.x * 12 + c];
        a0 += w0 * b2f_lo(v0.x) + w1 * b2f_lo(v1.x);
        a1 += w0 * b2f_hi(v0.x) + w1 * b2f_hi(v1.x);
        a2 += w0 * b2f_lo(v0.y) + w1 * b2f_lo(v1.y);
        a3 += w0 * b2f_hi(v0.y) + w1 * b2f_hi(v1.y);
        a4 += w0 * b2f_lo(v0.z) + w1 * b2f_lo(v1.z);
        a5 += w0 * b2f_hi(v0.z) + w1 * b2f_hi(v1.z);
        a6 += w0 * b2f_lo(v0.w) + w1 * b2f_lo(v1.w);
        a7 += w0 * b2f_hi(v0.w) + w1 * b2f_hi(v1.w);
    }
    if (o < s1) {
        int2 p0 = pr[o];
        float w0 = __int_as_float(p0.y);
        uint4 v0 = x[(size_t)p0.x * 12 + c];
        a0 += w0 * b2f_lo(v0.x); a1 += w0 * b2f_hi(v0.x);
        a2 += w0 * b2f_lo(v0.y); a3 += w0 * b2f_hi(v0.y);
        a4 += w0 * b2f_lo(v0.z); a5 += w0 * b2f_hi(v0.z);
        a6 += w0 * b2f_lo(v0.w); a7 += w0 * b2f_hi(v0.w);
    }
    size_t oi = (size_t)n * 12 + c;
    if (CHEBY) {
        uint4 bv = base[oi];
        a0 = 2.f * a0 - b2f_lo(bv.x); a1 = 2.f * a1 - b2f_hi(bv.x);
        a2 = 2.f * a2 - b2f_lo(bv.y); a3 = 2.f * a3 - b2f_hi(bv.y);
        a4 = 2.f * a4 - b2f_lo(bv.z); a5 = 2.f * a5 - b2f_hi(bv.z);
        a6 = 2.f * a6 - b2f_lo(bv.w); a7 = 2.f * a7 - b2f_hi(bv.w);
    }
    uint4 ov;
    ov.x = pack2(a0, a1); ov.y = pack2(a2, a3);
    ov.z = pack2(a4, a5); ov.w = pack2(a6, a7);
    out[oi] = ov;
}

// Fuse + swizzle gate weights into MFMA-fragment-linear bf16:
// wf[kt][ct][lane][j]  = Wl[kt*32 + (lane>>4)*8 + j][ct*16 + (lane&15)]
// Wl = [480][64] with K segments {W00+W10, W01, W11, W02, W12}. grid.x = gate.
__global__ void prep_weights_kernel(const float* __restrict__ Wz, const float* __restrict__ Wr,
                                    const float* __restrict__ Wh, u16* __restrict__ wf_all) {
    const int KS = 96 * 64;
    int g = blockIdx.x;
    const float* W = (g == 0) ? Wz : (g == 1) ? Wr : Wh;
    u16* wf = wf_all + (size_t)g * 30720;
    for (int i = threadIdx.x; i < 30720; i += blockDim.x) {
        int j = i & 7, lane = (i >> 3) & 63, ct = (i >> 9) & 3, kt = i >> 11;
        int k = kt * 32 + (lane >> 4) * 8 + j;
        int col = ct * 16 + (lane & 15);
        int m = k / 96, fr = k - m * 96;
        int off = (m == 0) ? 0 : (m == 1) ? KS : (m == 2) ? 4 * KS : (m == 3) ? 2 * KS : 5 * KS;
        float v = W[off + fr * 64 + col];
        if (m == 0) v += W[3 * KS + fr * 64 + col];
        wf[i] = f2b(v);
    }
}

// MFMA GEMM: C[N,64] = sum_m A_m[N,96] @ W_m  (A bf16, W pre-swizzled bf16 in LDS).
// Block = 512 threads = 8 waves; block covers 128 rows; wave w covers rows [128b+16w, +16).
// MODE 0: Out = sigmoid(acc)              (Z gate, f32)
// MODE 1: XH[:,32:96] = H * sigmoid(acc)  (R gate, bf16, in place)
// MODE 2: Out = Z*H + (1-Z)*tanh(acc)     (H~ + GRU combine, f32)
template <int MODE>
__global__ __launch_bounds__(512) void gemm_mfma_kernel(
    const u16* __restrict__ A0, const u16* __restrict__ A1, const u16* __restrict__ A2,
    const u16* __restrict__ A3, const u16* __restrict__ A4,
    const u16* __restrict__ wfrag, const float* __restrict__ bias,
    const float* __restrict__ H, const float* __restrict__ Z,
    void* __restrict__ OutP, int N) {
    __shared__ u16 wl[30720];  // 61440 B -> 2 blocks/CU
    int t = threadIdx.x;
    {
        const uint4* src = (const uint4*)wfrag;
        uint4* dst = (uint4*)wl;
        for (int i = t; i < 3840; i += 512) dst[i] = src[i];
    }
    __syncthreads();

    int lane = t & 63, w = t >> 6;
    int rowBase = blockIdx.x * 128 + w * 16;
    int arow = rowBase + (lane & 15);
    size_t aoff = (size_t)arow * 96 + (lane >> 4) * 8;  // bf16 elements

    f32x4 acc[4];
#pragma unroll
    for (int ct = 0; ct < 4; ++ct) {
        float b = bias[ct * 16 + (lane & 15)];
        acc[ct] = (f32x4){b, b, b, b};
    }

    const u16* As[5] = {A0, A1, A2, A3, A4};
#pragma unroll
    for (int m = 0; m < 5; ++m) {
        const u16* Am = As[m];
#pragma unroll
        for (int k3 = 0; k3 < 3; ++k3) {
            short8 a = *(const short8*)(Am + aoff + k3 * 32);
            int ktg = m * 3 + k3;
#pragma unroll
            for (int ct = 0; ct < 4; ++ct) {
                short8 b = *(const short8*)(&wl[((ktg * 4 + ct) * 64 + lane) * 8]);
                acc[ct] = __builtin_amdgcn_mfma_f32_16x16x32_bf16(a, b, acc[ct], 0, 0, 0);
            }
        }
    }

    // Epilogue: lane covers col = ct*16 + (lane&15), rows (lane>>4)*4 + j.
    int rsub = (lane >> 4) * 4;
#pragma unroll
    for (int ct = 0; ct < 4; ++ct) {
        int col = ct * 16 + (lane & 15);
#pragma unroll
        for (int j = 0; j < 4; ++j) {
            int grow = rowBase + rsub + j;
            if (grow >= N) continue;
            float v = acc[ct][j];
            size_t bi = (size_t)grow * 64 + col;
            if (MODE == 0) {
                ((float*)OutP)[bi] = sigmoidf_(v);
            } else if (MODE == 1) {
                ((u16*)OutP)[(size_t)grow * 96 + 32 + col] = f2b(H[bi] * sigmoidf_(v));
            } else {
                float z = Z[bi];
                ((float*)OutP)[bi] = z * H[bi] + (1.f - z) * tanhf(v);
            }
        }
    }
}

// ---------------------------------------------------------------- launch

extern "C" void kernel_launch(void* const* d_in, const int* in_sizes, int n_in,
                              void* d_out, int out_size, void* d_ws, size_t ws_size,
                              hipStream_t stream) {
    const float* X  = (const float*)d_in[0];
    const int*   ei = (const int*)d_in[1];
    const float* ew = (const float*)d_in[2];
    const float* H  = (const float*)d_in[3];
    const float* Wz = (const float*)d_in[4];
    const float* bz = (const float*)d_in[5];
    const float* Wr = (const float*)d_in[6];
    const float* br = (const float*)d_in[7];
    const float* Wh = (const float*)d_in[8];
    const float* bh = (const float*)d_in[9];
    float* out = (float*)d_out;

    const int N = in_sizes[0] / 32;   // 50000
    const int E = in_sizes[2];        // 800000
    const int NB = (N + BKT_NODES - 1) >> BKT_BITS;  // 49 (code assumes NB <= 64)

    // ---- workspace carve (256B aligned) ----
    char* wp = (char*)d_ws;
    auto alloc = [&](size_t nbytes) -> void* {
        void* p = (void*)wp;
        wp += (nbytes + 255) & ~(size_t)255;
        return p;
    };
    u16* XH   = (u16*)alloc((size_t)N * 96 * 2);  // becomes XHR after R-GEMM
    u16* T1o  = (u16*)alloc((size_t)N * 96 * 2);
    u16* T1i  = (u16*)alloc((size_t)N * 96 * 2);
    u16* S2o  = (u16*)alloc((size_t)N * 96 * 2);
    u16* S2i  = (u16*)alloc((size_t)N * 96 * 2);
    float* AccZ = (float*)alloc((size_t)N * 64 * 4);
    float* deg_in  = (float*)alloc((size_t)N * 4);
    float* deg_out = (float*)alloc((size_t)N * 4);
    int* offs_f = (int*)alloc((size_t)(N + 1) * 4);
    int* offs_b = (int*)alloc((size_t)(N + 1) * 4);
    int2* pair_f = (int2*)alloc((size_t)E * 8);
    int2* pair_b = (int2*)alloc((size_t)E * 8);
    uint2* stgF = (uint2*)alloc((size_t)NB * STG_CAP * 8);
    uint2* stgB = (uint2*)alloc((size_t)NB * STG_CAP * 8);
    u16* wf_all = (u16*)alloc((size_t)3 * 30720 * 2);
    int* gCntF  = (int*)alloc(64 * 4);
    int* gCntB  = (int*)alloc(64 * 4);
    int* bBaseF = (int*)alloc(65 * 4);
    int* bBaseB = (int*)alloc(65 * 4);
    int* flag   = (int*)alloc(256);

    const int xhBlocks = (N * 12 + NTHREADS - 1) / NTHREADS;
    const int gemmBlocks = (N + 127) / 128;
    const int binBlocks = (E + 4095) / 4096;
    dim3 gatherBlock(12, 32);
    dim3 gatherGrid((N + 31) / 32, 2);

    // ---- edge preprocessing (bucketed CSR build) ----
    hipMemsetAsync(gCntF, 0, 64 * 4, stream);
    hipMemsetAsync(gCntB, 0, 64 * 4, stream);

    detect_i64_kernel<<<1, 256, 0, stream>>>(ei, E < 8192 ? E : 8192, flag);
    prep_weights_kernel<<<3, 256, 0, stream>>>(Wz, Wr, Wh, wf_all);
    bin_kernel<<<binBlocks, 1024, 0, stream>>>(ei, flag, ew, gCntF, gCntB, stgF, stgB, E, NB);
    bktscan_kernel<<<1, 64, 0, stream>>>(gCntF, gCntB, bBaseF, bBaseB, offs_f, offs_b, NB, N, E);
    bktdeg_kernel<<<2 * NB, 1024, 0, stream>>>(stgF, stgB, gCntF, gCntB, deg_in, deg_out, N, NB);
    bktcsr_kernel<<<2 * NB, 1024, 0, stream>>>(stgF, stgB, gCntF, gCntB, bBaseF, bBaseB,
                                               deg_in, deg_out, offs_f, offs_b,
                                               pair_f, pair_b, N, NB);

    // ---- phase ZR: shared T matrices on XH = [X|H] ----
    build_xh_kernel<<<xhBlocks, NTHREADS, 0, stream>>>((const float4*)X, (const float4*)H,
                                                       (uint4*)XH, N);
    gather2_kernel<0><<<gatherGrid, gatherBlock, 0, stream>>>(
        (const uint4*)XH, (const uint4*)XH, offs_f, pair_f, offs_b, pair_b,
        nullptr, (uint4*)T1o, (uint4*)T1i, N);
    gather2_kernel<1><<<gatherGrid, gatherBlock, 0, stream>>>(
        (const uint4*)T1o, (const uint4*)T1i, offs_f, pair_f, offs_b, pair_b,
        (const uint4*)XH, (uint4*)S2o, (uint4*)S2i, N);

    // Z gate (sigmoid fused), R gate (H*R written into XH in place -> XHR)
    gemm_mfma_kernel<0><<<gemmBlocks, 512, 0, stream>>>(
        XH, T1o, T1i, S2o, S2i, wf_all, bz, nullptr, nullptr, AccZ, N);
    gemm_mfma_kernel<1><<<gemmBlocks, 512, 0, stream>>>(
        XH, T1o, T1i, S2o, S2i, wf_all + 30720, br, H, nullptr, XH, N);

    // ---- phase H: propagate XHR ----
    gather2_kernel<0><<<gatherGrid, gatherBlock, 0, stream>>>(
        (const uint4*)XH, (const uint4*)XH, offs_f, pair_f, offs_b, pair_b,
        nullptr, (uint4*)T1o, (uint4*)T1i, N);
    gather2_kernel<1><<<gatherGrid, gatherBlock, 0, stream>>>(
        (const uint4*)T1o, (const uint4*)T1i, offs_f, pair_f, offs_b, pair_b,
        (const uint4*)XH, (uint4*)S2o, (uint4*)S2i, N);

    // H~ gate + GRU combine fused
    gemm_mfma_kernel<2><<<gemmBlocks, 512, 0, stream>>>(
        XH, T1o, T1i, S2o, S2i, wf_all + 2 * 30720, bh, H, AccZ, out, N);
}